// Round 3
// baseline (1379.634 us; speedup 1.0000x reference)
//
#include <hip/hip_runtime.h>

// Dtype-adaptive implementation: k_probe sniffs whether d_in[] holds fp32
// (per the reference: jnp.float32) or harness-bf16-ified data; all kernels
// load true inputs via runtime flag[0]; intermediates are bf16 (flag[1]==0).
//
// Workspace (19,530,760 B): out1 bf16 8,388,608 | raw bf16 8,388,608 |
// wT fp32 2,359,296 | tmtr fp32 393,216 | stats 1,024 | flag u32[2]

typedef unsigned int u32;
typedef unsigned short u16;

#define HW 4096
#define CHW 1048576

static __device__ __forceinline__ float bf2f(u16 u) {
    union { u32 i; float f; } c; c.i = ((u32)u) << 16; return c.f;
}
static __device__ __forceinline__ u16 f2bf(float f) {
    union { float f; u32 i; } c; c.f = f;
    u32 x = c.i;
    return (u16)((x + 0x7FFFu + ((x >> 16) & 1u)) >> 16);   // RNE
}
static __device__ __forceinline__ float loadv(const void* p, long i, int f32) {
    return f32 ? ((const float*)p)[i] : bf2f(((const u16*)p)[i]);
}

__global__ __launch_bounds__(256) void k_probe(const u32* __restrict__ xw,
                                               u32* __restrict__ flag) {
    __shared__ int cnt;
    if (threadIdx.x == 0) cnt = 0;
    __syncthreads();
    union { u32 i; float f; } c;
    c.i = xw[threadIdx.x * 997];
    float a = fabsf(c.f);
    if (a > 1e-8f && a < 1e4f) atomicAdd(&cnt, 1);
    __syncthreads();
    if (threadIdx.x == 0) { flag[0] = (cnt >= 128) ? 1u : 0u; flag[1] = 0u; }
}

__global__ __launch_bounds__(256) void k_transpose_w(const void* __restrict__ wdc,
                                                     const u32* __restrict__ flag,
                                                     float* __restrict__ wT) {
    const int f32 = (int)flag[0];
    int i = blockIdx.x * 256 + threadIdx.x;
    int o = i / 2304;
    int ck = i - o * 2304;
    wT[ck * 256 + o] = loadv(wdc, i, f32);
}

// src dtype = flag[srcsel]; weights/biases dtype = flag[0]
__global__ __launch_bounds__(256) void k_conv_offsets(
    const void* __restrict__ src,
    const void* __restrict__ w_tm, const void* __restrict__ b_tm,
    const void* __restrict__ w_tr, const void* __restrict__ b_tr,
    const u32* __restrict__ flag, int srcsel,
    float* __restrict__ tmtr)
{
    __shared__ float wt[13824];
    __shared__ float nb[8][3][64];
    const int wf32 = (int)flag[0];
    const int sf32 = (int)flag[srcsel];
    const int tid = threadIdx.x;
    for (int i = tid; i < 13824; i += 256) {
        int oc = i / 2304;
        int r  = i - oc * 2304;
        wt[i] = (oc < 4) ? loadv(w_tm, (long)oc * 2304 + r, wf32)
                         : loadv(w_tr, (long)(oc - 4) * 2304 + r, wf32);
    }
    const int bid = blockIdx.x;
    const int n = bid >> 6, h = bid & 63;
    const int w = tid & 63;
    const int ocq = tid >> 6;
    const int oc1 = (ocq < 2) ? (4 + ocq) : -1;
    float acc0 = 0.f, acc1 = 0.f;
    const long nbase = (long)n * CHW;

    for (int cb = 0; cb < 256; cb += 8) {
        __syncthreads();
        for (int e = tid; e < 1536; e += 256) {
            int c   = e / 192;
            int rr  = (e >> 6) % 3;
            int ww2 = e & 63;
            int row = h - 1 + rr;
            float v = 0.f;
            if (row >= 0 && row < 64)
                v = loadv(src, nbase + (long)(cb + c) * HW + row * 64 + ww2, sf32);
            nb[c][rr][ww2] = v;
        }
        __syncthreads();
        for (int c = 0; c < 8; ++c) {
            float v[9];
            #pragma unroll
            for (int rr = 0; rr < 3; ++rr) {
                v[rr * 3 + 0] = (w >= 1)  ? nb[c][rr][w - 1] : 0.f;
                v[rr * 3 + 1] = nb[c][rr][w];
                v[rr * 3 + 2] = (w <= 62) ? nb[c][rr][w + 1] : 0.f;
            }
            const float* w0 = &wt[ocq * 2304 + (cb + c) * 9];
            #pragma unroll
            for (int k = 0; k < 9; ++k) acc0 = fmaf(v[k], w0[k], acc0);
            if (oc1 >= 0) {
                const float* w1 = &wt[oc1 * 2304 + (cb + c) * 9];
                #pragma unroll
                for (int k = 0; k < 9; ++k) acc1 = fmaf(v[k], w1[k], acc1);
            }
        }
    }
    tmtr[((long)n * 6 + ocq) * HW + h * 64 + w] = acc0 + loadv(b_tm, ocq, wf32);
    if (oc1 >= 0)
        tmtr[((long)n * 6 + oc1) * HW + h * 64 + w] = acc1 + loadv(b_tr, oc1 - 4, wf32);
}

__global__ __launch_bounds__(512) void k_deform(
    const void* __restrict__ src, const float* __restrict__ tmtr,
    const float* __restrict__ wT, const u32* __restrict__ flag, int srcsel,
    u16* __restrict__ raw)
{
    __shared__ __align__(16) float s_lds[4 * 9 * 64];
    __shared__ __align__(16) float wt_lds[4 * 9 * 256];
    __shared__ int   g_y0[576];
    __shared__ int   g_x0[576];
    __shared__ float g_wy[576];
    __shared__ float g_wx[576];

    const int sf32 = (int)flag[srcsel];
    const int tid = threadIdx.x;
    const int bid = blockIdx.x;
    const int n = bid >> 6, h = bid & 63;
    const float* tb = tmtr + (long)n * 6 * HW + h * 64;

    for (int i = tid; i < 576; i += 512) {
        int k = i >> 6, ww2 = i & 63;
        float m00 = tb[ww2],          m01 = tb[HW + ww2];
        float m10 = tb[2 * HW + ww2], m11 = tb[3 * HW + ww2];
        float tr0 = tb[4 * HW + ww2], tr1 = tb[5 * HW + ww2];
        float ry = (float)(k / 3) - 1.f;
        float rx = (float)(k % 3) - 1.f;
        float dy = m00 * ry + m01 * rx - ry + tr0;
        float dx = m10 * ry + m11 * rx - rx + tr1;
        float py = (float)h + ry + dy;
        float px = (float)ww2 + rx + dx;
        float y0f = floorf(py), x0f = floorf(px);
        g_y0[i] = (int)y0f; g_x0[i] = (int)x0f;
        g_wy[i] = py - y0f; g_wx[i] = px - x0f;
    }
    __syncthreads();

    const long nbase = (long)n * CHW;
    const int og = tid >> 3;
    const int wg = tid & 7;
    float acc[4][8];
    #pragma unroll
    for (int i = 0; i < 4; ++i)
        #pragma unroll
        for (int j = 0; j < 8; ++j) acc[i][j] = 0.f;

    for (int cb = 0; cb < 256; cb += 4) {
        if (cb) __syncthreads();
        {
            const float4* wsrc = (const float4*)(wT + (long)cb * 2304);
            float4* wdst = (float4*)wt_lds;
            for (int i = tid; i < 2304; i += 512) wdst[i] = wsrc[i];
        }
        for (int e = tid; e < 2304; e += 512) {
            int c   = e / 576;
            int r   = e - c * 576;
            int k   = r >> 6;
            int ww2 = r & 63;
            int gi  = k * 64 + ww2;
            int y0 = g_y0[gi], x0 = g_x0[gi];
            float wy1 = g_wy[gi], wx1 = g_wx[gi];
            float wy0 = 1.f - wy1, wx0 = 1.f - wx1;
            long cbase = nbase + (long)(cb + c) * HW;
            bool yi0 = (y0 >= 0) && (y0 < 64);
            bool yi1 = (y0 + 1 >= 0) && (y0 + 1 < 64);
            bool xi0 = (x0 >= 0) && (x0 < 64);
            bool xi1 = (x0 + 1 >= 0) && (x0 + 1 < 64);
            float v00 = (yi0 && xi0) ? loadv(src, cbase + y0 * 64 + x0, sf32)           : 0.f;
            float v01 = (yi0 && xi1) ? loadv(src, cbase + y0 * 64 + x0 + 1, sf32)       : 0.f;
            float v10 = (yi1 && xi0) ? loadv(src, cbase + (y0 + 1) * 64 + x0, sf32)     : 0.f;
            float v11 = (yi1 && xi1) ? loadv(src, cbase + (y0 + 1) * 64 + x0 + 1, sf32) : 0.f;
            s_lds[(c * 9 + k) * 64 + ww2] = wy0 * (wx0 * v00 + wx1 * v01)
                                          + wy1 * (wx0 * v10 + wx1 * v11);
        }
        __syncthreads();
        for (int c = 0; c < 4; ++c) {
            #pragma unroll
            for (int k = 0; k < 9; ++k) {
                const float* wp = &wt_lds[(c * 9 + k) * 256 + (og << 2)];
                const float* sp = &s_lds[(c * 9 + k) * 64 + (wg << 3)];
                float4 wv = *(const float4*)wp;
                float4 sa = *(const float4*)sp;
                float4 sb = *(const float4*)(sp + 4);
                float wvv[4] = {wv.x, wv.y, wv.z, wv.w};
                float sv[8]  = {sa.x, sa.y, sa.z, sa.w, sb.x, sb.y, sb.z, sb.w};
                #pragma unroll
                for (int i2 = 0; i2 < 4; ++i2)
                    #pragma unroll
                    for (int j2 = 0; j2 < 8; ++j2)
                        acc[i2][j2] = fmaf(wvv[i2], sv[j2], acc[i2][j2]);
            }
        }
    }
    #pragma unroll
    for (int i = 0; i < 4; ++i) {
        long elem = nbase + (long)(og * 4 + i) * HW + h * 64 + (wg << 3);
        uint4 pk;
        pk.x = (u32)f2bf(acc[i][0]) | ((u32)f2bf(acc[i][1]) << 16);
        pk.y = (u32)f2bf(acc[i][2]) | ((u32)f2bf(acc[i][3]) << 16);
        pk.z = (u32)f2bf(acc[i][4]) | ((u32)f2bf(acc[i][5]) << 16);
        pk.w = (u32)f2bf(acc[i][6]) | ((u32)f2bf(acc[i][7]) << 16);
        *(uint4*)(raw + elem) = pk;
    }
}

__global__ __launch_bounds__(256) void k_gn_stats(const u16* __restrict__ raw,
                                                  float* __restrict__ stats) {
    const int b = blockIdx.x;
    const uint4* base = (const uint4*)(raw + (long)b * 32768);
    const int tid = threadIdx.x;
    float s1 = 0.f, s2 = 0.f;
    for (int i = tid; i < 4096; i += 256) {
        uint4 p = base[i];
        u32 ww[4] = {p.x, p.y, p.z, p.w};
        #pragma unroll
        for (int q = 0; q < 4; ++q) {
            float a = bf2f((u16)(ww[q] & 0xFFFFu));
            float bb = bf2f((u16)(ww[q] >> 16));
            s1 += a + bb;
            s2 += a * a + bb * bb;
        }
    }
    #pragma unroll
    for (int off = 32; off; off >>= 1) {
        s1 += __shfl_down(s1, off, 64);
        s2 += __shfl_down(s2, off, 64);
    }
    __shared__ float r1[4], r2[4];
    if ((tid & 63) == 0) { r1[tid >> 6] = s1; r2[tid >> 6] = s2; }
    __syncthreads();
    if (tid == 0) {
        float t1 = r1[0] + r1[1] + r1[2] + r1[3];
        float t2 = r2[0] + r2[1] + r2[2] + r2[3];
        const float inv = 1.f / 32768.f;
        float mean = t1 * inv;
        float var = t2 * inv - mean * mean;
        stats[b * 2] = mean;
        stats[b * 2 + 1] = rsqrtf(var + 1e-5f);
    }
}

__global__ __launch_bounds__(256) void k_gn_relu(
    const u16* __restrict__ raw, const float* __restrict__ stats,
    const void* __restrict__ gamma, const void* __restrict__ beta,
    const u32* __restrict__ flag,
    u16* __restrict__ out1)
{
    const int f32 = (int)flag[0];
    const int i = blockIdx.x * 256 + threadIdx.x;
    const int e = i << 3;
    const int c = (e >> 12) & 255;
    const int ng = (e >> 20) * 32 + (c >> 3);
    float mean = stats[ng * 2], rstd = stats[ng * 2 + 1];
    float ga = loadv(gamma, c, f32) * rstd;
    float be = loadv(beta, c, f32) - mean * ga;
    uint4 p = ((const uint4*)raw)[i];
    u32 ww[4] = {p.x, p.y, p.z, p.w};
    u32 oo[4];
    #pragma unroll
    for (int q = 0; q < 4; ++q) {
        float a = fmaxf(fmaf(bf2f((u16)(ww[q] & 0xFFFFu)), ga, be), 0.f);
        float b = fmaxf(fmaf(bf2f((u16)(ww[q] >> 16)),     ga, be), 0.f);
        oo[q] = (u32)f2bf(a) | ((u32)f2bf(b) << 16);
    }
    uint4 o; o.x = oo[0]; o.y = oo[1]; o.z = oo[2]; o.w = oo[3];
    ((uint4*)out1)[i] = o;
}

__global__ __launch_bounds__(256) void k_gn_final(
    const u16* __restrict__ raw, const float* __restrict__ stats,
    const void* __restrict__ gamma, const void* __restrict__ beta,
    const void* __restrict__ x, const u32* __restrict__ flag,
    void* __restrict__ outp)
{
    const int f32 = (int)flag[0];
    const int i = blockIdx.x * 256 + threadIdx.x;
    const int e = i << 3;
    const int c = (e >> 12) & 255;
    const int ng = (e >> 20) * 32 + (c >> 3);
    float mean = stats[ng * 2], rstd = stats[ng * 2 + 1];
    float ga = loadv(gamma, c, f32) * rstd;
    float be = loadv(beta, c, f32) - mean * ga;
    uint4 p = ((const uint4*)raw)[i];
    u32 ww[4] = {p.x, p.y, p.z, p.w};
    float v[8];
    #pragma unroll
    for (int q = 0; q < 4; ++q) {
        v[2 * q + 0] = fmaxf(fmaf(bf2f((u16)(ww[q] & 0xFFFFu)), ga, be) + loadv(x, (long)e + 2 * q + 0, f32), 0.f);
        v[2 * q + 1] = fmaxf(fmaf(bf2f((u16)(ww[q] >> 16)),     ga, be) + loadv(x, (long)e + 2 * q + 1, f32), 0.f);
    }
    if (f32) {
        float4* op = (float4*)((float*)outp + e);
        op[0] = make_float4(v[0], v[1], v[2], v[3]);
        op[1] = make_float4(v[4], v[5], v[6], v[7]);
    } else {
        uint4 o;
        o.x = (u32)f2bf(v[0]) | ((u32)f2bf(v[1]) << 16);
        o.y = (u32)f2bf(v[2]) | ((u32)f2bf(v[3]) << 16);
        o.z = (u32)f2bf(v[4]) | ((u32)f2bf(v[5]) << 16);
        o.w = (u32)f2bf(v[6]) | ((u32)f2bf(v[7]) << 16);
        ((uint4*)outp)[i] = o;
    }
}

extern "C" void kernel_launch(void* const* d_in, const int* in_sizes, int n_in,
                              void* d_out, int out_size, void* d_ws, size_t ws_size,
                              hipStream_t stream) {
    const void* x     = d_in[0];
    const void* w_tm1 = d_in[1];
    const void* b_tm1 = d_in[2];
    const void* w_tr1 = d_in[3];
    const void* b_tr1 = d_in[4];
    const void* w_dc1 = d_in[5];
    const void* g1    = d_in[6];
    const void* be1   = d_in[7];
    const void* w_tm2 = d_in[8];
    const void* b_tm2 = d_in[9];
    const void* w_tr2 = d_in[10];
    const void* b_tr2 = d_in[11];
    const void* w_dc2 = d_in[12];
    const void* g2    = d_in[13];
    const void* be2   = d_in[14];

    char* wsb = (char*)d_ws;
    u16*   out1  = (u16*)wsb;
    u16*   raw   = (u16*)(wsb + 8388608);
    float* wT    = (float*)(wsb + 16777216);
    float* tmtr  = (float*)(wsb + 16777216 + 2359296);
    float* stats = (float*)(wsb + 16777216 + 2359296 + 393216);
    u32*   flag  = (u32*)(wsb + 16777216 + 2359296 + 393216 + 1024);

    k_probe<<<1, 256, 0, stream>>>((const u32*)x, flag);
    // flag[0] = dtype of true inputs (1=fp32, 0=bf16); flag[1] = 0 (bf16)

    // ---- round 1 (src = x, dtype flag[0]) ----
    k_transpose_w <<<2304, 256, 0, stream>>>(w_dc1, flag, wT);
    k_conv_offsets<<<256, 256, 0, stream>>>(x, w_tm1, b_tm1, w_tr1, b_tr1, flag, 0, tmtr);
    k_deform      <<<256, 512, 0, stream>>>(x, tmtr, wT, flag, 0, raw);
    k_gn_stats    <<<128, 256, 0, stream>>>(raw, stats);
    k_gn_relu     <<<2048, 256, 0, stream>>>(raw, stats, g1, be1, flag, out1);
    // ---- round 2 (src = out1, always bf16 -> srcsel=1) ----
    k_transpose_w <<<2304, 256, 0, stream>>>(w_dc2, flag, wT);
    k_conv_offsets<<<256, 256, 0, stream>>>(out1, w_tm2, b_tm2, w_tr2, b_tr2, flag, 1, tmtr);
    k_deform      <<<256, 512, 0, stream>>>(out1, tmtr, wT, flag, 1, raw);
    k_gn_stats    <<<128, 256, 0, stream>>>(raw, stats);
    k_gn_final    <<<2048, 256, 0, stream>>>(raw, stats, g2, be2, x, flag, d_out);
}

// Round 4
// 769.175 us; speedup vs baseline: 1.7937x; 1.7937x over previous
//
#include <hip/hip_runtime.h>

// Dtype-adaptive pipeline; deform conv now runs on MFMA (bf16 16x16x32).
// Workspace: out1 bf16 8,388,608 | raw bf16 8,388,608 | wTg bf16 1,179,648 |
// tmtr fp32 393,216 | stats 1,024 | flag u32[2]   (total ~18.4 MB)

typedef unsigned int u32;
typedef unsigned short u16;
typedef __attribute__((ext_vector_type(8))) short bf16x8;
typedef __attribute__((ext_vector_type(4))) float floatx4;

#define HW 4096
#define CHW 1048576

static __device__ __forceinline__ float bf2f(u16 u) {
    union { u32 i; float f; } c; c.i = ((u32)u) << 16; return c.f;
}
static __device__ __forceinline__ u16 f2bf(float f) {
    union { float f; u32 i; } c; c.f = f;
    u32 x = c.i;
    return (u16)((x + 0x7FFFu + ((x >> 16) & 1u)) >> 16);   // RNE
}
static __device__ __forceinline__ float loadv(const void* p, long i, int f32) {
    return f32 ? ((const float*)p)[i] : bf2f(((const u16*)p)[i]);
}

__global__ __launch_bounds__(256) void k_probe(const u32* __restrict__ xw,
                                               u32* __restrict__ flag) {
    __shared__ int cnt;
    if (threadIdx.x == 0) cnt = 0;
    __syncthreads();
    union { u32 i; float f; } c;
    c.i = xw[threadIdx.x * 997];
    float a = fabsf(c.f);
    if (a > 1e-8f && a < 1e4f) atomicAdd(&cnt, 1);
    __syncthreads();
    if (threadIdx.x == 0) { flag[0] = (cnt >= 128) ? 1u : 0u; flag[1] = 0u; }
}

// ---------------------------------------------------------------------------
// Pack deform weights for MFMA staging:
// w_dc [o][c][kk]  ->  wTg[((kk*8 + c/32)*256 + o)*32 + (c%32)]   (bf16)
// Chunk q = kk*8+cb is 8192 contiguous bf16 (16 KB), LDS-layout-ready.
// ---------------------------------------------------------------------------
__global__ __launch_bounds__(256) void k_prep_w(const void* __restrict__ wdc,
                                                const u32* __restrict__ flag,
                                                u16* __restrict__ wTg) {
    const int f32 = (int)flag[0];
    int i = blockIdx.x * 256 + threadIdx.x;   // 2304 blocks
    int o = i / 2304;
    int r = i - o * 2304;
    int c = r / 9;
    int kk = r - c * 9;
    wTg[((((kk << 3) + (c >> 5)) * 256 + o) << 5) + (c & 31)] = f2bf(loadv(wdc, i, f32));
}

// ---------------------------------------------------------------------------
// 6-channel 3x3 conv (tm: oc 0..3, tr: oc 4..5), pad=1. (unchanged)
// ---------------------------------------------------------------------------
__global__ __launch_bounds__(256) void k_conv_offsets(
    const void* __restrict__ src,
    const void* __restrict__ w_tm, const void* __restrict__ b_tm,
    const void* __restrict__ w_tr, const void* __restrict__ b_tr,
    const u32* __restrict__ flag, int srcsel,
    float* __restrict__ tmtr)
{
    __shared__ float wt[13824];
    __shared__ float nb[8][3][64];
    const int wf32 = (int)flag[0];
    const int sf32 = (int)flag[srcsel];
    const int tid = threadIdx.x;
    for (int i = tid; i < 13824; i += 256) {
        int oc = i / 2304;
        int r  = i - oc * 2304;
        wt[i] = (oc < 4) ? loadv(w_tm, (long)oc * 2304 + r, wf32)
                         : loadv(w_tr, (long)(oc - 4) * 2304 + r, wf32);
    }
    const int bid = blockIdx.x;
    const int n = bid >> 6, h = bid & 63;
    const int w = tid & 63;
    const int ocq = tid >> 6;
    const int oc1 = (ocq < 2) ? (4 + ocq) : -1;
    float acc0 = 0.f, acc1 = 0.f;
    const long nbase = (long)n * CHW;

    for (int cb = 0; cb < 256; cb += 8) {
        __syncthreads();
        for (int e = tid; e < 1536; e += 256) {
            int c   = e / 192;
            int rr  = (e >> 6) % 3;
            int ww2 = e & 63;
            int row = h - 1 + rr;
            float v = 0.f;
            if (row >= 0 && row < 64)
                v = loadv(src, nbase + (long)(cb + c) * HW + row * 64 + ww2, sf32);
            nb[c][rr][ww2] = v;
        }
        __syncthreads();
        for (int c = 0; c < 8; ++c) {
            float v[9];
            #pragma unroll
            for (int rr = 0; rr < 3; ++rr) {
                v[rr * 3 + 0] = (w >= 1)  ? nb[c][rr][w - 1] : 0.f;
                v[rr * 3 + 1] = nb[c][rr][w];
                v[rr * 3 + 2] = (w <= 62) ? nb[c][rr][w + 1] : 0.f;
            }
            const float* w0 = &wt[ocq * 2304 + (cb + c) * 9];
            #pragma unroll
            for (int k = 0; k < 9; ++k) acc0 = fmaf(v[k], w0[k], acc0);
            if (oc1 >= 0) {
                const float* w1 = &wt[oc1 * 2304 + (cb + c) * 9];
                #pragma unroll
                for (int k = 0; k < 9; ++k) acc1 = fmaf(v[k], w1[k], acc1);
            }
        }
    }
    tmtr[((long)n * 6 + ocq) * HW + h * 64 + w] = acc0 + loadv(b_tm, ocq, wf32);
    if (oc1 >= 0)
        tmtr[((long)n * 6 + oc1) * HW + h * 64 + w] = acc1 + loadv(b_tr, oc1 - 4, wf32);
}

// ---------------------------------------------------------------------------
// MFMA deform conv. One block (512 thr = 8 waves) per (n,h) row.
// GEMM: D[256o][64w] = W[256o][K'=2304] * S[K'][64w], K' = k*256+c.
// Chunk q = k*8+cb covers 32 channels of one k-tap (geometry constant).
// LDS: W[o][32c] and S[w][32c], row stride 40 bf16 (80 B = 20 banks: 2-way,
// free). A/B frags are single ds_read_b128 each. Double-buffered, 1 sync/chunk.
// ---------------------------------------------------------------------------
__global__ __launch_bounds__(512) void k_deform(
    const void* __restrict__ src, const float* __restrict__ tmtr,
    const u16* __restrict__ wTg, const u32* __restrict__ flag, int srcsel,
    u16* __restrict__ raw)
{
    __shared__ __align__(16) short Wl[2][256 * 40];   // 40960 B
    __shared__ __align__(16) short Sl[2][64 * 40];    // 10240 B
    __shared__ int   g_y0[576];
    __shared__ int   g_x0[576];
    __shared__ float g_wy[576];
    __shared__ float g_wx[576];

    const int sf32 = (int)flag[srcsel];
    const int tid = threadIdx.x;
    const int bid = blockIdx.x;
    const int n = bid >> 6, h = bid & 63;
    const float* tb = tmtr + (long)n * 6 * HW + h * 64;

    for (int i = tid; i < 576; i += 512) {            // (k,w) geometry
        int k = i >> 6, ww2 = i & 63;
        float m00 = tb[ww2],          m01 = tb[HW + ww2];
        float m10 = tb[2 * HW + ww2], m11 = tb[3 * HW + ww2];
        float tr0 = tb[4 * HW + ww2], tr1 = tb[5 * HW + ww2];
        float ry = (float)(k / 3) - 1.f;
        float rx = (float)(k % 3) - 1.f;
        float dy = m00 * ry + m01 * rx - ry + tr0;
        float dx = m10 * ry + m11 * rx - rx + tr1;
        float py = (float)h + ry + dy;
        float px = (float)ww2 + rx + dx;
        float y0f = floorf(py), x0f = floorf(px);
        g_y0[i] = (int)y0f; g_x0[i] = (int)x0f;
        g_wy[i] = py - y0f; g_wx[i] = px - x0f;
    }
    __syncthreads();

    const long nbase = (long)n * CHW;
    // sampler role: w = lane, c-quad = wave
    const int sw  = tid & 63;
    const int scq = tid >> 6;
    // W-stage role
    const int wo = tid >> 1;
    const int whalf = tid & 1;
    // MFMA role
    const int lane = tid & 63;
    const int quad = lane >> 4;
    const int l16  = lane & 15;
    const int o0   = (tid >> 6) << 5;   // wave's o-base (32 per wave)

    floatx4 acc[2][4];
    #pragma unroll
    for (int i = 0; i < 2; ++i)
        #pragma unroll
        for (int j = 0; j < 4; ++j)
            acc[i][j] = (floatx4){0.f, 0.f, 0.f, 0.f};

    // per-k cached sampler state (validity folded into corner weights)
    int a00 = 0, a01 = 0, a10 = 0, a11 = 0;
    float cw00 = 0.f, cw01 = 0.f, cw10 = 0.f, cw11 = 0.f;
    int cur_k = -1;

    auto stage = [&](int q, int b) {
        const int k = q >> 3, cb = q & 7;
        if (k != cur_k) {
            cur_k = k;
            int gi = k * 64 + sw;
            int y0 = g_y0[gi], x0 = g_x0[gi];
            float wy1 = g_wy[gi], wx1 = g_wx[gi];
            float wy0 = 1.f - wy1, wx0 = 1.f - wx1;
            bool yv0 = (y0 >= 0) && (y0 < 64);
            bool yv1 = (y0 >= -1) && (y0 < 63);
            bool xv0 = (x0 >= 0) && (x0 < 64);
            bool xv1 = (x0 >= -1) && (x0 < 63);
            int yc0 = min(max(y0, 0), 63),     yc1 = min(max(y0 + 1, 0), 63);
            int xc0 = min(max(x0, 0), 63),     xc1 = min(max(x0 + 1, 0), 63);
            a00 = yc0 * 64 + xc0; a01 = yc0 * 64 + xc1;
            a10 = yc1 * 64 + xc0; a11 = yc1 * 64 + xc1;
            cw00 = (yv0 && xv0) ? wy0 * wx0 : 0.f;
            cw01 = (yv0 && xv1) ? wy0 * wx1 : 0.f;
            cw10 = (yv1 && xv0) ? wy1 * wx0 : 0.f;
            cw11 = (yv1 && xv1) ? wy1 * wx1 : 0.f;
        }
        // --- W stage: chunk is 8192 contiguous bf16; 16 per thread ---
        const uint4* gp = (const uint4*)(wTg + (((size_t)q * 256 + wo) << 5) + (whalf << 4));
        uint4 wv0 = gp[0], wv1 = gp[1];
        *(uint4*)&Wl[b][wo * 40 + whalf * 16]     = wv0;
        *(uint4*)&Wl[b][wo * 40 + whalf * 16 + 8] = wv1;
        // --- S stage: 4 channels per thread, shared geometry ---
        const int cbase = cb * 32 + scq * 4;
        u16 pk[4];
        #pragma unroll
        for (int u = 0; u < 4; ++u) {
            long coff = nbase + ((long)(cbase + u) << 12);
            float v00 = loadv(src, coff + a00, sf32);
            float v01 = loadv(src, coff + a01, sf32);
            float v10 = loadv(src, coff + a10, sf32);
            float v11 = loadv(src, coff + a11, sf32);
            pk[u] = f2bf(fmaf(cw00, v00, fmaf(cw01, v01, fmaf(cw10, v10, cw11 * v11))));
        }
        uint2 pkk;
        pkk.x = (u32)pk[0] | ((u32)pk[1] << 16);
        pkk.y = (u32)pk[2] | ((u32)pk[3] << 16);
        *(uint2*)&Sl[b][sw * 40 + scq * 4] = pkk;
    };

    auto compute = [&](int b) {
        bf16x8 av0 = *(const bf16x8*)&Wl[b][(o0 + l16) * 40 + quad * 8];
        bf16x8 av1 = *(const bf16x8*)&Wl[b][(o0 + 16 + l16) * 40 + quad * 8];
        #pragma unroll
        for (int j = 0; j < 4; ++j) {
            bf16x8 bv = *(const bf16x8*)&Sl[b][(j * 16 + l16) * 40 + quad * 8];
            acc[0][j] = __builtin_amdgcn_mfma_f32_16x16x32_bf16(av0, bv, acc[0][j], 0, 0, 0);
            acc[1][j] = __builtin_amdgcn_mfma_f32_16x16x32_bf16(av1, bv, acc[1][j], 0, 0, 0);
        }
    };

    stage(0, 0);
    __syncthreads();
    for (int q = 0; q < 72; ++q) {
        if (q + 1 < 72) stage(q + 1, (q + 1) & 1);
        compute(q & 1);
        __syncthreads();
    }

    // epilogue: D[o][w], o = o0 + i*16 + quad*4 + r, w = j*16 + l16
    #pragma unroll
    for (int i = 0; i < 2; ++i)
        #pragma unroll
        for (int j = 0; j < 4; ++j)
            #pragma unroll
            for (int r = 0; r < 4; ++r) {
                int o = o0 + i * 16 + quad * 4 + r;
                raw[nbase + ((long)o << 12) + (h << 6) + j * 16 + l16] = f2bf(acc[i][j][r]);
            }
}

// ---------------------------------------------------------------------------
__global__ __launch_bounds__(256) void k_gn_stats(const u16* __restrict__ raw,
                                                  float* __restrict__ stats) {
    const int b = blockIdx.x;
    const uint4* base = (const uint4*)(raw + (long)b * 32768);
    const int tid = threadIdx.x;
    float s1 = 0.f, s2 = 0.f;
    for (int i = tid; i < 4096; i += 256) {
        uint4 p = base[i];
        u32 ww[4] = {p.x, p.y, p.z, p.w};
        #pragma unroll
        for (int q = 0; q < 4; ++q) {
            float a = bf2f((u16)(ww[q] & 0xFFFFu));
            float bb = bf2f((u16)(ww[q] >> 16));
            s1 += a + bb;
            s2 += a * a + bb * bb;
        }
    }
    #pragma unroll
    for (int off = 32; off; off >>= 1) {
        s1 += __shfl_down(s1, off, 64);
        s2 += __shfl_down(s2, off, 64);
    }
    __shared__ float r1[4], r2[4];
    if ((tid & 63) == 0) { r1[tid >> 6] = s1; r2[tid >> 6] = s2; }
    __syncthreads();
    if (tid == 0) {
        float t1 = r1[0] + r1[1] + r1[2] + r1[3];
        float t2 = r2[0] + r2[1] + r2[2] + r2[3];
        const float inv = 1.f / 32768.f;
        float mean = t1 * inv;
        float var = t2 * inv - mean * mean;
        stats[b * 2] = mean;
        stats[b * 2 + 1] = rsqrtf(var + 1e-5f);
    }
}

__global__ __launch_bounds__(256) void k_gn_relu(
    const u16* __restrict__ raw, const float* __restrict__ stats,
    const void* __restrict__ gamma, const void* __restrict__ beta,
    const u32* __restrict__ flag,
    u16* __restrict__ out1)
{
    const int f32 = (int)flag[0];
    const int i = blockIdx.x * 256 + threadIdx.x;
    const int e = i << 3;
    const int c = (e >> 12) & 255;
    const int ng = (e >> 20) * 32 + (c >> 3);
    float mean = stats[ng * 2], rstd = stats[ng * 2 + 1];
    float ga = loadv(gamma, c, f32) * rstd;
    float be = loadv(beta, c, f32) - mean * ga;
    uint4 p = ((const uint4*)raw)[i];
    u32 ww[4] = {p.x, p.y, p.z, p.w};
    u32 oo[4];
    #pragma unroll
    for (int q = 0; q < 4; ++q) {
        float a = fmaxf(fmaf(bf2f((u16)(ww[q] & 0xFFFFu)), ga, be), 0.f);
        float b = fmaxf(fmaf(bf2f((u16)(ww[q] >> 16)),     ga, be), 0.f);
        oo[q] = (u32)f2bf(a) | ((u32)f2bf(b) << 16);
    }
    uint4 o; o.x = oo[0]; o.y = oo[1]; o.z = oo[2]; o.w = oo[3];
    ((uint4*)out1)[i] = o;
}

__global__ __launch_bounds__(256) void k_gn_final(
    const u16* __restrict__ raw, const float* __restrict__ stats,
    const void* __restrict__ gamma, const void* __restrict__ beta,
    const void* __restrict__ x, const u32* __restrict__ flag,
    void* __restrict__ outp)
{
    const int f32 = (int)flag[0];
    const int i = blockIdx.x * 256 + threadIdx.x;
    const int e = i << 3;
    const int c = (e >> 12) & 255;
    const int ng = (e >> 20) * 32 + (c >> 3);
    float mean = stats[ng * 2], rstd = stats[ng * 2 + 1];
    float ga = loadv(gamma, c, f32) * rstd;
    float be = loadv(beta, c, f32) - mean * ga;
    uint4 p = ((const uint4*)raw)[i];
    u32 ww[4] = {p.x, p.y, p.z, p.w};
    float v[8];
    #pragma unroll
    for (int q = 0; q < 4; ++q) {
        v[2 * q + 0] = fmaxf(fmaf(bf2f((u16)(ww[q] & 0xFFFFu)), ga, be) + loadv(x, (long)e + 2 * q + 0, f32), 0.f);
        v[2 * q + 1] = fmaxf(fmaf(bf2f((u16)(ww[q] >> 16)),     ga, be) + loadv(x, (long)e + 2 * q + 1, f32), 0.f);
    }
    if (f32) {
        float4* op = (float4*)((float*)outp + e);
        op[0] = make_float4(v[0], v[1], v[2], v[3]);
        op[1] = make_float4(v[4], v[5], v[6], v[7]);
    } else {
        uint4 o;
        o.x = (u32)f2bf(v[0]) | ((u32)f2bf(v[1]) << 16);
        o.y = (u32)f2bf(v[2]) | ((u32)f2bf(v[3]) << 16);
        o.z = (u32)f2bf(v[4]) | ((u32)f2bf(v[5]) << 16);
        o.w = (u32)f2bf(v[6]) | ((u32)f2bf(v[7]) << 16);
        ((uint4*)outp)[i] = o;
    }
}

extern "C" void kernel_launch(void* const* d_in, const int* in_sizes, int n_in,
                              void* d_out, int out_size, void* d_ws, size_t ws_size,
                              hipStream_t stream) {
    const void* x     = d_in[0];
    const void* w_tm1 = d_in[1];
    const void* b_tm1 = d_in[2];
    const void* w_tr1 = d_in[3];
    const void* b_tr1 = d_in[4];
    const void* w_dc1 = d_in[5];
    const void* g1    = d_in[6];
    const void* be1   = d_in[7];
    const void* w_tm2 = d_in[8];
    const void* b_tm2 = d_in[9];
    const void* w_tr2 = d_in[10];
    const void* b_tr2 = d_in[11];
    const void* w_dc2 = d_in[12];
    const void* g2    = d_in[13];
    const void* be2   = d_in[14];

    char* wsb = (char*)d_ws;
    u16*   out1  = (u16*)wsb;                                   // 8,388,608 B
    u16*   raw   = (u16*)(wsb + 8388608);                       // 8,388,608 B
    u16*   wTg   = (u16*)(wsb + 16777216);                      // 1,179,648 B
    float* tmtr  = (float*)(wsb + 16777216 + 1179648);          //   393,216 B
    float* stats = (float*)(wsb + 16777216 + 1179648 + 393216); //     1,024 B
    u32*   flag  = (u32*)(wsb + 16777216 + 1179648 + 393216 + 1024);

    k_probe<<<1, 256, 0, stream>>>((const u32*)x, flag);

    // ---- round 1 (src = x, dtype flag[0]) ----
    k_prep_w      <<<2304, 256, 0, stream>>>(w_dc1, flag, wTg);
    k_conv_offsets<<<256, 256, 0, stream>>>(x, w_tm1, b_tm1, w_tr1, b_tr1, flag, 0, tmtr);
    k_deform      <<<256, 512, 0, stream>>>(x, tmtr, wTg, flag, 0, raw);
    k_gn_stats    <<<128, 256, 0, stream>>>(raw, stats);
    k_gn_relu     <<<2048, 256, 0, stream>>>(raw, stats, g1, be1, flag, out1);
    // ---- round 2 (src = out1, always bf16 -> srcsel=1) ----
    k_prep_w      <<<2304, 256, 0, stream>>>(w_dc2, flag, wTg);
    k_conv_offsets<<<256, 256, 0, stream>>>(out1, w_tm2, b_tm2, w_tr2, b_tr2, flag, 1, tmtr);
    k_deform      <<<256, 512, 0, stream>>>(out1, tmtr, wTg, flag, 1, raw);
    k_gn_stats    <<<128, 256, 0, stream>>>(raw, stats);
    k_gn_final    <<<2048, 256, 0, stream>>>(raw, stats, g2, be2, x, flag, d_out);
}

// Round 5
// 530.994 us; speedup vs baseline: 2.5982x; 1.4486x over previous
//
#include <hip/hip_runtime.h>

// NHWC-sampled MFMA deform conv pipeline.
// ws: xT/out1 (bf16 NHWC, aliased) 8 MB | raw (bf16 NCHW) 8 MB |
//     wTg 1.18 MB | tmtr 0.39 MB | stats 1 KB | flag 8 B   (~17.96 MB)

typedef unsigned int u32;
typedef unsigned short u16;
typedef __attribute__((ext_vector_type(8))) short bf16x8;
typedef __attribute__((ext_vector_type(4))) float floatx4;

#define HW 4096
#define CHW 1048576

static __device__ __forceinline__ float bf2f(u16 u) {
    union { u32 i; float f; } c; c.i = ((u32)u) << 16; return c.f;
}
static __device__ __forceinline__ u16 f2bf(float f) {
    union { float f; u32 i; } c; c.f = f;
    u32 x = c.i;
    return (u16)((x + 0x7FFFu + ((x >> 16) & 1u)) >> 16);   // RNE
}
static __device__ __forceinline__ float loadv(const void* p, long i, int f32) {
    return f32 ? ((const float*)p)[i] : bf2f(((const u16*)p)[i]);
}

__global__ __launch_bounds__(256) void k_probe(const u32* __restrict__ xw,
                                               u32* __restrict__ flag) {
    __shared__ int cnt;
    if (threadIdx.x == 0) cnt = 0;
    __syncthreads();
    union { u32 i; float f; } c;
    c.i = xw[threadIdx.x * 997];
    float a = fabsf(c.f);
    if (a > 1e-8f && a < 1e4f) atomicAdd(&cnt, 1);
    __syncthreads();
    if (threadIdx.x == 0) { flag[0] = (cnt >= 128) ? 1u : 0u; flag[1] = 0u; }
}

// ---------------------------------------------------------------------------
// NCHW (flag dtype) -> NHWC bf16.  Scattered 4B reads (L2-absorbed),
// coalesced 16B writes.  Grid 2048 x 256.
// ---------------------------------------------------------------------------
__global__ __launch_bounds__(256) void k_to_nhwc(const void* __restrict__ src,
                                                 const u32* __restrict__ flag,
                                                 u16* __restrict__ dst) {
    const int f32 = (int)flag[0];
    int i = blockIdx.x * 256 + threadIdx.x;   // 524288 threads
    int cq  = i & 31;
    int pix = i >> 5;          // n*4096 + hw
    int n   = pix >> 12;
    int hw  = pix & 4095;
    long sbase = (long)n * CHW + hw;
    u16 v[8];
    #pragma unroll
    for (int j = 0; j < 8; ++j)
        v[j] = f2bf(loadv(src, sbase + (long)(cq * 8 + j) * HW, f32));
    uint4 o;
    o.x = (u32)v[0] | ((u32)v[1] << 16);
    o.y = (u32)v[2] | ((u32)v[3] << 16);
    o.z = (u32)v[4] | ((u32)v[5] << 16);
    o.w = (u32)v[6] | ((u32)v[7] << 16);
    *(uint4*)&dst[(long)n * CHW + (long)hw * 256 + cq * 8] = o;
}

// ---------------------------------------------------------------------------
// Pack deform weights: w_dc [o][c][kk] -> wTg[(kk*8 + c/32)*256 + o][c%32]
// ---------------------------------------------------------------------------
__global__ __launch_bounds__(256) void k_prep_w(const void* __restrict__ wdc,
                                                const u32* __restrict__ flag,
                                                u16* __restrict__ wTg) {
    const int f32 = (int)flag[0];
    int i = blockIdx.x * 256 + threadIdx.x;   // 2304 blocks
    int o = i / 2304;
    int r = i - o * 2304;
    int c = r / 9;
    int kk = r - c * 9;
    wTg[((((kk << 3) + (c >> 5)) * 256 + o) << 5) + (c & 31)] = f2bf(loadv(wdc, i, f32));
}

// ---------------------------------------------------------------------------
// 6-channel 3x3 conv, pad=1.  src layout: nhwc==0 -> NCHW (dtype flag[srcsel]),
// nhwc==1 -> NHWC bf16.
// ---------------------------------------------------------------------------
__global__ __launch_bounds__(256) void k_conv_offsets(
    const void* __restrict__ src,
    const void* __restrict__ w_tm, const void* __restrict__ b_tm,
    const void* __restrict__ w_tr, const void* __restrict__ b_tr,
    const u32* __restrict__ flag, int srcsel, int nhwc,
    float* __restrict__ tmtr)
{
    __shared__ float wt[13824];
    __shared__ float nb[8][3][64];
    const int wf32 = (int)flag[0];
    const int sf32 = (int)flag[srcsel];
    const int tid = threadIdx.x;
    for (int i = tid; i < 13824; i += 256) {
        int oc = i / 2304;
        int r  = i - oc * 2304;
        wt[i] = (oc < 4) ? loadv(w_tm, (long)oc * 2304 + r, wf32)
                         : loadv(w_tr, (long)(oc - 4) * 2304 + r, wf32);
    }
    const int bid = blockIdx.x;
    const int n = bid >> 6, h = bid & 63;
    const int w = tid & 63;
    const int ocq = tid >> 6;
    const int oc1 = (ocq < 2) ? (4 + ocq) : -1;
    float acc0 = 0.f, acc1 = 0.f;
    const long nbase = (long)n * CHW;

    for (int cb = 0; cb < 256; cb += 8) {
        __syncthreads();
        if (nhwc) {
            const u16* sp = (const u16*)src;
            for (int e = tid; e < 1536; e += 256) {
                int c   = e & 7;
                int ww2 = (e >> 3) & 63;
                int rr  = e >> 9;
                int row = h - 1 + rr;
                float v = 0.f;
                if (row >= 0 && row < 64)
                    v = bf2f(sp[nbase + (long)(row * 64 + ww2) * 256 + cb + c]);
                nb[c][rr][ww2] = v;
            }
        } else {
            for (int e = tid; e < 1536; e += 256) {
                int c   = e / 192;
                int rr  = (e >> 6) % 3;
                int ww2 = e & 63;
                int row = h - 1 + rr;
                float v = 0.f;
                if (row >= 0 && row < 64)
                    v = loadv(src, nbase + (long)(cb + c) * HW + row * 64 + ww2, sf32);
                nb[c][rr][ww2] = v;
            }
        }
        __syncthreads();
        for (int c = 0; c < 8; ++c) {
            float v[9];
            #pragma unroll
            for (int rr = 0; rr < 3; ++rr) {
                v[rr * 3 + 0] = (w >= 1)  ? nb[c][rr][w - 1] : 0.f;
                v[rr * 3 + 1] = nb[c][rr][w];
                v[rr * 3 + 2] = (w <= 62) ? nb[c][rr][w + 1] : 0.f;
            }
            const float* w0 = &wt[ocq * 2304 + (cb + c) * 9];
            #pragma unroll
            for (int k = 0; k < 9; ++k) acc0 = fmaf(v[k], w0[k], acc0);
            if (oc1 >= 0) {
                const float* w1 = &wt[oc1 * 2304 + (cb + c) * 9];
                #pragma unroll
                for (int k = 0; k < 9; ++k) acc1 = fmaf(v[k], w1[k], acc1);
            }
        }
    }
    tmtr[((long)n * 6 + ocq) * HW + h * 64 + w] = acc0 + loadv(b_tm, ocq, wf32);
    if (oc1 >= 0)
        tmtr[((long)n * 6 + oc1) * HW + h * 64 + w] = acc1 + loadv(b_tr, oc1 - 4, wf32);
}

// ---------------------------------------------------------------------------
// MFMA deform conv, NHWC bf16 source.  One block (8 waves) per (n,h) row.
// Chunk q = k*8+cb: 32 channels of one k-tap (constant geometry).
// ---------------------------------------------------------------------------
__global__ __launch_bounds__(512) void k_deform(
    const u16* __restrict__ srcT, const float* __restrict__ tmtr,
    const u16* __restrict__ wTg, u16* __restrict__ raw)
{
    __shared__ __align__(16) short Wl[2][256 * 40];   // 40960 B
    __shared__ __align__(16) short Sl[2][64 * 40];    // 10240 B
    __shared__ int   g_y0[576];
    __shared__ int   g_x0[576];
    __shared__ float g_wy[576];
    __shared__ float g_wx[576];

    const int tid = threadIdx.x;
    const int bid = blockIdx.x;
    const int n = bid >> 6, h = bid & 63;
    const float* tb = tmtr + (long)n * 6 * HW + h * 64;

    for (int i = tid; i < 576; i += 512) {            // (k,w) geometry
        int k = i >> 6, ww2 = i & 63;
        float m00 = tb[ww2],          m01 = tb[HW + ww2];
        float m10 = tb[2 * HW + ww2], m11 = tb[3 * HW + ww2];
        float tr0 = tb[4 * HW + ww2], tr1 = tb[5 * HW + ww2];
        float ry = (float)(k / 3) - 1.f;
        float rx = (float)(k % 3) - 1.f;
        float dy = m00 * ry + m01 * rx - ry + tr0;
        float dx = m10 * ry + m11 * rx - rx + tr1;
        float py = (float)h + ry + dy;
        float px = (float)ww2 + rx + dx;
        float y0f = floorf(py), x0f = floorf(px);
        g_y0[i] = (int)y0f; g_x0[i] = (int)x0f;
        g_wy[i] = py - y0f; g_wx[i] = px - x0f;
    }
    __syncthreads();

    const long nbase = (long)n * CHW;
    const u16* sp = srcT + nbase;
    // sampler role: w = tid>>3 (8 lanes/w share it via cq)
    const int sw  = tid >> 3;
    const int scq = tid & 7;
    // W-stage role
    const int wo = tid >> 1;
    const int whalf = tid & 1;
    // MFMA role
    const int lane = tid & 63;
    const int quad = lane >> 4;
    const int l16  = lane & 15;
    const int o0   = (tid >> 6) << 5;

    floatx4 acc[2][4];
    #pragma unroll
    for (int i = 0; i < 2; ++i)
        #pragma unroll
        for (int j = 0; j < 4; ++j)
            acc[i][j] = (floatx4){0.f, 0.f, 0.f, 0.f};

    int a00 = 0, a01 = 0, a10 = 0, a11 = 0;           // pixel indices
    float cw00 = 0.f, cw01 = 0.f, cw10 = 0.f, cw11 = 0.f;
    int cur_k = -1;

    auto stage = [&](int q, int b) {
        const int k = q >> 3, cb = q & 7;
        if (k != cur_k) {
            cur_k = k;
            int gi = k * 64 + sw;
            int y0 = g_y0[gi], x0 = g_x0[gi];
            float wy1 = g_wy[gi], wx1 = g_wx[gi];
            float wy0 = 1.f - wy1, wx0 = 1.f - wx1;
            bool yv0 = (y0 >= 0) && (y0 < 64);
            bool yv1 = (y0 >= -1) && (y0 < 63);
            bool xv0 = (x0 >= 0) && (x0 < 64);
            bool xv1 = (x0 >= -1) && (x0 < 63);
            int yc0 = min(max(y0, 0), 63),     yc1 = min(max(y0 + 1, 0), 63);
            int xc0 = min(max(x0, 0), 63),     xc1 = min(max(x0 + 1, 0), 63);
            a00 = yc0 * 64 + xc0; a01 = yc0 * 64 + xc1;
            a10 = yc1 * 64 + xc0; a11 = yc1 * 64 + xc1;
            cw00 = (yv0 && xv0) ? wy0 * wx0 : 0.f;
            cw01 = (yv0 && xv1) ? wy0 * wx1 : 0.f;
            cw10 = (yv1 && xv0) ? wy1 * wx0 : 0.f;
            cw11 = (yv1 && xv1) ? wy1 * wx1 : 0.f;
        }
        // --- W stage: 8192 contiguous bf16 per chunk ---
        const uint4* gp = (const uint4*)(wTg + (((size_t)q * 256 + wo) << 5) + (whalf << 4));
        uint4 wv0 = gp[0], wv1 = gp[1];
        // --- S stage: 4 contiguous channels x 4 corners (NHWC) ---
        const int cc = cb * 32 + scq * 4;
        uint2 r00 = *(const uint2*)&sp[(long)a00 * 256 + cc];
        uint2 r01 = *(const uint2*)&sp[(long)a01 * 256 + cc];
        uint2 r10 = *(const uint2*)&sp[(long)a10 * 256 + cc];
        uint2 r11 = *(const uint2*)&sp[(long)a11 * 256 + cc];
        *(uint4*)&Wl[b][wo * 40 + whalf * 16]     = wv0;
        *(uint4*)&Wl[b][wo * 40 + whalf * 16 + 8] = wv1;
        u32 c00[2] = {r00.x, r00.y}, c01[2] = {r01.x, r01.y};
        u32 c10[2] = {r10.x, r10.y}, c11[2] = {r11.x, r11.y};
        u16 pk[4];
        #pragma unroll
        for (int u = 0; u < 4; ++u) {
            int hi = u >> 1, sh = (u & 1) << 4;
            float v00 = bf2f((u16)(c00[hi] >> sh));
            float v01 = bf2f((u16)(c01[hi] >> sh));
            float v10 = bf2f((u16)(c10[hi] >> sh));
            float v11 = bf2f((u16)(c11[hi] >> sh));
            pk[u] = f2bf(fmaf(cw00, v00, fmaf(cw01, v01, fmaf(cw10, v10, cw11 * v11))));
        }
        uint2 pkk;
        pkk.x = (u32)pk[0] | ((u32)pk[1] << 16);
        pkk.y = (u32)pk[2] | ((u32)pk[3] << 16);
        *(uint2*)&Sl[b][sw * 40 + scq * 4] = pkk;
    };

    auto compute = [&](int b) {
        bf16x8 av0 = *(const bf16x8*)&Wl[b][(o0 + l16) * 40 + quad * 8];
        bf16x8 av1 = *(const bf16x8*)&Wl[b][(o0 + 16 + l16) * 40 + quad * 8];
        #pragma unroll
        for (int j = 0; j < 4; ++j) {
            bf16x8 bv = *(const bf16x8*)&Sl[b][(j * 16 + l16) * 40 + quad * 8];
            acc[0][j] = __builtin_amdgcn_mfma_f32_16x16x32_bf16(av0, bv, acc[0][j], 0, 0, 0);
            acc[1][j] = __builtin_amdgcn_mfma_f32_16x16x32_bf16(av1, bv, acc[1][j], 0, 0, 0);
        }
    };

    stage(0, 0);
    __syncthreads();
    for (int q = 0; q < 72; ++q) {
        if (q + 1 < 72) stage(q + 1, (q + 1) & 1);
        compute(q & 1);
        __syncthreads();
    }

    #pragma unroll
    for (int i = 0; i < 2; ++i)
        #pragma unroll
        for (int j = 0; j < 4; ++j)
            #pragma unroll
            for (int r = 0; r < 4; ++r) {
                int o = o0 + i * 16 + quad * 4 + r;
                raw[nbase + ((long)o << 12) + (h << 6) + j * 16 + l16] = f2bf(acc[i][j][r]);
            }
}

// ---------------------------------------------------------------------------
__global__ __launch_bounds__(256) void k_gn_stats(const u16* __restrict__ raw,
                                                  float* __restrict__ stats) {
    const int b = blockIdx.x;
    const uint4* base = (const uint4*)(raw + (long)b * 32768);
    const int tid = threadIdx.x;
    float s1 = 0.f, s2 = 0.f;
    for (int i = tid; i < 4096; i += 256) {
        uint4 p = base[i];
        u32 ww[4] = {p.x, p.y, p.z, p.w};
        #pragma unroll
        for (int q = 0; q < 4; ++q) {
            float a = bf2f((u16)(ww[q] & 0xFFFFu));
            float bb = bf2f((u16)(ww[q] >> 16));
            s1 += a + bb;
            s2 += a * a + bb * bb;
        }
    }
    #pragma unroll
    for (int off = 32; off; off >>= 1) {
        s1 += __shfl_down(s1, off, 64);
        s2 += __shfl_down(s2, off, 64);
    }
    __shared__ float r1[4], r2[4];
    if ((tid & 63) == 0) { r1[tid >> 6] = s1; r2[tid >> 6] = s2; }
    __syncthreads();
    if (tid == 0) {
        float t1 = r1[0] + r1[1] + r1[2] + r1[3];
        float t2 = r2[0] + r2[1] + r2[2] + r2[3];
        const float inv = 1.f / 32768.f;
        float mean = t1 * inv;
        float var = t2 * inv - mean * mean;
        stats[b * 2] = mean;
        stats[b * 2 + 1] = rsqrtf(var + 1e-5f);
    }
}

// ---------------------------------------------------------------------------
// GN + relu; reads raw (NCHW bf16), writes out1 (NHWC bf16) via LDS transpose.
// One block per (n,h).
// ---------------------------------------------------------------------------
__global__ __launch_bounds__(256) void k_gn_relu(
    const u16* __restrict__ raw, const float* __restrict__ stats,
    const void* __restrict__ gamma, const void* __restrict__ beta,
    const u32* __restrict__ flag,
    u16* __restrict__ out1)
{
    __shared__ u16 T[64 * 258];
    const int f32 = (int)flag[0];
    const int bid = blockIdx.x;
    const int n = bid >> 6, h = bid & 63;
    const int tid = threadIdx.x;
    const u16* rb = raw + (long)n * CHW + (h << 6);
    for (int it = 0; it < 64; ++it) {
        int e = it * 256 + tid;
        int c = e >> 6, w = e & 63;
        int ng = n * 32 + (c >> 3);
        float rstd = stats[ng * 2 + 1];
        float ga = loadv(gamma, c, f32) * rstd;
        float be = loadv(beta, c, f32) - stats[ng * 2] * ga;
        float v = fmaxf(fmaf(bf2f(rb[(long)c * HW + w]), ga, be), 0.f);
        T[w * 258 + c] = f2bf(v);
    }
    __syncthreads();
    const int w = tid >> 2, cq = tid & 3;
    const u32* Tr = (const u32*)T;   // row w at word 129*w
    u16* ob = out1 + (long)n * CHW + (long)((h << 6) + w) * 256 + cq * 64;
    #pragma unroll
    for (int s = 0; s < 8; ++s) {
        uint4 o;
        o.x = Tr[129 * w + 32 * cq + 4 * s + 0];
        o.y = Tr[129 * w + 32 * cq + 4 * s + 1];
        o.z = Tr[129 * w + 32 * cq + 4 * s + 2];
        o.w = Tr[129 * w + 32 * cq + 4 * s + 3];
        *(uint4*)&ob[s * 8] = o;
    }
}

// ---------------------------------------------------------------------------
__global__ __launch_bounds__(256) void k_gn_final(
    const u16* __restrict__ raw, const float* __restrict__ stats,
    const void* __restrict__ gamma, const void* __restrict__ beta,
    const void* __restrict__ x, const u32* __restrict__ flag,
    void* __restrict__ outp)
{
    const int f32 = (int)flag[0];
    const int i = blockIdx.x * 256 + threadIdx.x;
    const int e = i << 3;
    const int c = (e >> 12) & 255;
    const int ng = (e >> 20) * 32 + (c >> 3);
    float mean = stats[ng * 2], rstd = stats[ng * 2 + 1];
    float ga = loadv(gamma, c, f32) * rstd;
    float be = loadv(beta, c, f32) - mean * ga;
    uint4 p = ((const uint4*)raw)[i];
    u32 ww[4] = {p.x, p.y, p.z, p.w};
    float v[8];
    #pragma unroll
    for (int q = 0; q < 4; ++q) {
        v[2 * q + 0] = fmaxf(fmaf(bf2f((u16)(ww[q] & 0xFFFFu)), ga, be) + loadv(x, (long)e + 2 * q + 0, f32), 0.f);
        v[2 * q + 1] = fmaxf(fmaf(bf2f((u16)(ww[q] >> 16)),     ga, be) + loadv(x, (long)e + 2 * q + 1, f32), 0.f);
    }
    if (f32) {
        float4* op = (float4*)((float*)outp + e);
        op[0] = make_float4(v[0], v[1], v[2], v[3]);
        op[1] = make_float4(v[4], v[5], v[6], v[7]);
    } else {
        uint4 o;
        o.x = (u32)f2bf(v[0]) | ((u32)f2bf(v[1]) << 16);
        o.y = (u32)f2bf(v[2]) | ((u32)f2bf(v[3]) << 16);
        o.z = (u32)f2bf(v[4]) | ((u32)f2bf(v[5]) << 16);
        o.w = (u32)f2bf(v[6]) | ((u32)f2bf(v[7]) << 16);
        ((uint4*)outp)[i] = o;
    }
}

extern "C" void kernel_launch(void* const* d_in, const int* in_sizes, int n_in,
                              void* d_out, int out_size, void* d_ws, size_t ws_size,
                              hipStream_t stream) {
    const void* x     = d_in[0];
    const void* w_tm1 = d_in[1];
    const void* b_tm1 = d_in[2];
    const void* w_tr1 = d_in[3];
    const void* b_tr1 = d_in[4];
    const void* w_dc1 = d_in[5];
    const void* g1    = d_in[6];
    const void* be1   = d_in[7];
    const void* w_tm2 = d_in[8];
    const void* b_tm2 = d_in[9];
    const void* w_tr2 = d_in[10];
    const void* b_tr2 = d_in[11];
    const void* w_dc2 = d_in[12];
    const void* g2    = d_in[13];
    const void* be2   = d_in[14];

    char* wsb = (char*)d_ws;
    u16*   xT    = (u16*)wsb;                                   // 8,388,608 B (aliased: out1)
    u16*   raw   = (u16*)(wsb + 8388608);                       // 8,388,608 B
    u16*   wTg   = (u16*)(wsb + 16777216);                      // 1,179,648 B
    float* tmtr  = (float*)(wsb + 16777216 + 1179648);          //   393,216 B
    float* stats = (float*)(wsb + 16777216 + 1179648 + 393216); //     1,024 B
    u32*   flag  = (u32*)(wsb + 16777216 + 1179648 + 393216 + 1024);
    u16*   out1  = xT;   // xT is dead once round-1 deform finishes

    k_probe<<<1, 256, 0, stream>>>((const u32*)x, flag);

    // ---- round 1 (src = x NCHW dtype flag[0]; sampled via xT NHWC) ----
    k_to_nhwc     <<<2048, 256, 0, stream>>>(x, flag, xT);
    k_prep_w      <<<2304, 256, 0, stream>>>(w_dc1, flag, wTg);
    k_conv_offsets<<<256, 256, 0, stream>>>(x, w_tm1, b_tm1, w_tr1, b_tr1, flag, 0, 0, tmtr);
    k_deform      <<<256, 512, 0, stream>>>(xT, tmtr, wTg, raw);
    k_gn_stats    <<<128, 256, 0, stream>>>(raw, stats);
    k_gn_relu     <<<256, 256, 0, stream>>>(raw, stats, g1, be1, flag, out1);
    // ---- round 2 (src = out1 NHWC bf16) ----
    k_prep_w      <<<2304, 256, 0, stream>>>(w_dc2, flag, wTg);
    k_conv_offsets<<<256, 256, 0, stream>>>(out1, w_tm2, b_tm2, w_tr2, b_tr2, flag, 1, 1, tmtr);
    k_deform      <<<256, 512, 0, stream>>>(out1, tmtr, wTg, raw);
    k_gn_stats    <<<128, 256, 0, stream>>>(raw, stats);
    k_gn_final    <<<2048, 256, 0, stream>>>(raw, stats, g2, be2, x, flag, d_out);
}

// Round 6
// 332.746 us; speedup vs baseline: 4.1462x; 1.5958x over previous
//
#include <hip/hip_runtime.h>

// NHWC MFMA pipeline: offset-conv AND deform-conv both on matrix cores.
// ws: xT/out1 (NHWC bf16, aliased) 8 MB | raw (NCHW bf16) 8 MB | wTg 1.18 MB |
//     tmtr 0.39 MB | stats 1 KB | flag 16 B | wT6 73,728 B  (~17.6 MiB)

typedef unsigned int u32;
typedef unsigned short u16;
typedef __attribute__((ext_vector_type(8))) short bf16x8;
typedef __attribute__((ext_vector_type(4))) float floatx4;

#define HW 4096
#define CHW 1048576

static __device__ __forceinline__ float bf2f(u16 u) {
    union { u32 i; float f; } c; c.i = ((u32)u) << 16; return c.f;
}
static __device__ __forceinline__ u16 f2bf(float f) {
    union { float f; u32 i; } c; c.f = f;
    u32 x = c.i;
    return (u16)((x + 0x7FFFu + ((x >> 16) & 1u)) >> 16);   // RNE
}
static __device__ __forceinline__ float loadv(const void* p, long i, int f32) {
    return f32 ? ((const float*)p)[i] : bf2f(((const u16*)p)[i]);
}

__global__ __launch_bounds__(256) void k_probe(const u32* __restrict__ xw,
                                               u32* __restrict__ flag) {
    __shared__ int cnt;
    if (threadIdx.x == 0) cnt = 0;
    __syncthreads();
    union { u32 i; float f; } c;
    c.i = xw[threadIdx.x * 997];
    float a = fabsf(c.f);
    if (a > 1e-8f && a < 1e4f) atomicAdd(&cnt, 1);
    __syncthreads();
    if (threadIdx.x == 0) { flag[0] = (cnt >= 128) ? 1u : 0u; flag[1] = 0u; }
}

// ---------------------------------------------------------------------------
// NCHW (flag dtype) -> NHWC bf16.
// ---------------------------------------------------------------------------
__global__ __launch_bounds__(256) void k_to_nhwc(const void* __restrict__ src,
                                                 const u32* __restrict__ flag,
                                                 u16* __restrict__ dst) {
    const int f32 = (int)flag[0];
    int i = blockIdx.x * 256 + threadIdx.x;
    int cq  = i & 31;
    int pix = i >> 5;
    int n   = pix >> 12;
    int hw  = pix & 4095;
    long sbase = (long)n * CHW + hw;
    u16 v[8];
    #pragma unroll
    for (int j = 0; j < 8; ++j)
        v[j] = f2bf(loadv(src, sbase + (long)(cq * 8 + j) * HW, f32));
    uint4 o;
    o.x = (u32)v[0] | ((u32)v[1] << 16);
    o.y = (u32)v[2] | ((u32)v[3] << 16);
    o.z = (u32)v[4] | ((u32)v[5] << 16);
    o.w = (u32)v[6] | ((u32)v[7] << 16);
    *(uint4*)&dst[(long)n * CHW + (long)hw * 256 + cq * 8] = o;
}

// ---------------------------------------------------------------------------
// Pack deform weights: w_dc [o][c][kk] -> wTg[(kk*8 + c/32)*256 + o][c%32]
// ---------------------------------------------------------------------------
__global__ __launch_bounds__(256) void k_prep_w(const void* __restrict__ wdc,
                                                const u32* __restrict__ flag,
                                                u16* __restrict__ wTg) {
    const int f32 = (int)flag[0];
    int i = blockIdx.x * 256 + threadIdx.x;   // 2304 blocks
    int o = i / 2304;
    int r = i - o * 2304;
    int c = r / 9;
    int kk = r - c * 9;
    wTg[((((kk << 3) + (c >> 5)) * 256 + o) << 5) + (c & 31)] = f2bf(loadv(wdc, i, f32));
}

// ---------------------------------------------------------------------------
// Pack offset-conv weights: w_tm (4ch) + w_tr (2ch), [oc][c][k] ->
// wT6[q = k*8 + c/32][o(16, rows 6..15 zero)][c%32]  (bf16, 73,728 B)
// ---------------------------------------------------------------------------
__global__ __launch_bounds__(256) void k_prep_w6(const void* __restrict__ w_tm,
                                                 const void* __restrict__ w_tr,
                                                 const u32* __restrict__ flag,
                                                 u16* __restrict__ wT6) {
    const int f32 = (int)flag[0];
    int i = blockIdx.x * 256 + threadIdx.x;   // 144 blocks = 36864
    int q  = i >> 9;
    int o  = (i >> 5) & 15;
    int cc = i & 31;
    int k  = q >> 3;
    int c  = ((q & 7) << 5) + cc;
    float v = 0.f;
    if (o < 4)      v = loadv(w_tm, (long)o * 2304 + c * 9 + k, f32);
    else if (o < 6) v = loadv(w_tr, (long)(o - 4) * 2304 + c * 9 + k, f32);
    wT6[i] = f2bf(v);
}

// ---------------------------------------------------------------------------
// MFMA offset conv: D[6][64] per (n,h) row. src = NHWC bf16.
// 512 thr = 8 waves; wave wv does K-chunks q = wv*9 .. wv*9+8; A/B frags
// loaded DIRECTLY from global (no staging LDS); LDS only for 8-way reduce.
// ---------------------------------------------------------------------------
__global__ __launch_bounds__(512) void k_conv6(
    const u16* __restrict__ srcT, const u16* __restrict__ wT6,
    const void* __restrict__ b_tm, const void* __restrict__ b_tr,
    const u32* __restrict__ flag,
    float* __restrict__ tmtr)
{
    __shared__ float red[8][64][17];   // 34,816 B (pad 17 kills bank conflicts)
    const int tid = threadIdx.x;
    const int bid = blockIdx.x;        // n*64 + h
    const int n = bid >> 6, h = bid & 63;
    const int wv = tid >> 6;
    const int lane = tid & 63;
    const int quad = lane >> 4;
    const int l16 = lane & 15;
    const u16* sp = srcT + (long)n * CHW;

    floatx4 acc[4];
    #pragma unroll
    for (int j4 = 0; j4 < 4; ++j4) acc[j4] = (floatx4){0.f, 0.f, 0.f, 0.f};

    for (int qi = 0; qi < 9; ++qi) {
        const int q = wv * 9 + qi;
        const int k = q >> 3, cb = q & 7;
        const int ky = k / 3, kx = k % 3;
        const int row = h + ky - 1;
        const bool rv = (row >= 0) && (row < 64);
        bf16x8 av = *(const bf16x8*)&wT6[(((q << 4) + l16) << 5) + (quad << 3)];
        #pragma unroll
        for (int j4 = 0; j4 < 4; ++j4) {
            int w = (j4 << 4) + l16;
            int px = w + kx - 1;
            bf16x8 bv = {0, 0, 0, 0, 0, 0, 0, 0};
            if (rv && px >= 0 && px < 64)
                bv = *(const bf16x8*)&sp[(((long)(row << 6) + px) << 8) + (cb << 5) + (quad << 3)];
            acc[j4] = __builtin_amdgcn_mfma_f32_16x16x32_bf16(av, bv, acc[j4], 0, 0, 0);
        }
    }
    #pragma unroll
    for (int j4 = 0; j4 < 4; ++j4)
        #pragma unroll
        for (int r = 0; r < 4; ++r)
            red[wv][lane][(j4 << 2) + r] = acc[j4][r];
    __syncthreads();
    if (tid < 384) {
        const int o = tid >> 6, w = tid & 63;
        const int ln = ((o >> 2) << 4) + (w & 15);
        const int slot = ((w >> 4) << 2) + (o & 3);
        float s = 0.f;
        #pragma unroll
        for (int v = 0; v < 8; ++v) s += red[v][ln][slot];
        const int f32 = (int)flag[0];
        float bias = (o < 4) ? loadv(b_tm, o, f32) : loadv(b_tr, o - 4, f32);
        tmtr[((long)n * 6 + o) * HW + (h << 6) + w] = s + bias;
    }
}

// ---------------------------------------------------------------------------
// MFMA deform conv, NHWC bf16 source (unchanged from round 5).
// ---------------------------------------------------------------------------
__global__ __launch_bounds__(512) void k_deform(
    const u16* __restrict__ srcT, const float* __restrict__ tmtr,
    const u16* __restrict__ wTg, u16* __restrict__ raw)
{
    __shared__ __align__(16) short Wl[2][256 * 40];
    __shared__ __align__(16) short Sl[2][64 * 40];
    __shared__ int   g_y0[576];
    __shared__ int   g_x0[576];
    __shared__ float g_wy[576];
    __shared__ float g_wx[576];

    const int tid = threadIdx.x;
    const int bid = blockIdx.x;
    const int n = bid >> 6, h = bid & 63;
    const float* tb = tmtr + (long)n * 6 * HW + h * 64;

    for (int i = tid; i < 576; i += 512) {
        int k = i >> 6, ww2 = i & 63;
        float m00 = tb[ww2],          m01 = tb[HW + ww2];
        float m10 = tb[2 * HW + ww2], m11 = tb[3 * HW + ww2];
        float tr0 = tb[4 * HW + ww2], tr1 = tb[5 * HW + ww2];
        float ry = (float)(k / 3) - 1.f;
        float rx = (float)(k % 3) - 1.f;
        float dy = m00 * ry + m01 * rx - ry + tr0;
        float dx = m10 * ry + m11 * rx - rx + tr1;
        float py = (float)h + ry + dy;
        float px = (float)ww2 + rx + dx;
        float y0f = floorf(py), x0f = floorf(px);
        g_y0[i] = (int)y0f; g_x0[i] = (int)x0f;
        g_wy[i] = py - y0f; g_wx[i] = px - x0f;
    }
    __syncthreads();

    const long nbase = (long)n * CHW;
    const u16* sp = srcT + nbase;
    const int sw  = tid >> 3;
    const int scq = tid & 7;
    const int wo = tid >> 1;
    const int whalf = tid & 1;
    const int lane = tid & 63;
    const int quad = lane >> 4;
    const int l16  = lane & 15;
    const int o0   = (tid >> 6) << 5;

    floatx4 acc[2][4];
    #pragma unroll
    for (int i = 0; i < 2; ++i)
        #pragma unroll
        for (int j = 0; j < 4; ++j)
            acc[i][j] = (floatx4){0.f, 0.f, 0.f, 0.f};

    int a00 = 0, a01 = 0, a10 = 0, a11 = 0;
    float cw00 = 0.f, cw01 = 0.f, cw10 = 0.f, cw11 = 0.f;
    int cur_k = -1;

    auto stage = [&](int q, int b) {
        const int k = q >> 3, cb = q & 7;
        if (k != cur_k) {
            cur_k = k;
            int gi = k * 64 + sw;
            int y0 = g_y0[gi], x0 = g_x0[gi];
            float wy1 = g_wy[gi], wx1 = g_wx[gi];
            float wy0 = 1.f - wy1, wx0 = 1.f - wx1;
            bool yv0 = (y0 >= 0) && (y0 < 64);
            bool yv1 = (y0 >= -1) && (y0 < 63);
            bool xv0 = (x0 >= 0) && (x0 < 64);
            bool xv1 = (x0 >= -1) && (x0 < 63);
            int yc0 = min(max(y0, 0), 63),     yc1 = min(max(y0 + 1, 0), 63);
            int xc0 = min(max(x0, 0), 63),     xc1 = min(max(x0 + 1, 0), 63);
            a00 = yc0 * 64 + xc0; a01 = yc0 * 64 + xc1;
            a10 = yc1 * 64 + xc0; a11 = yc1 * 64 + xc1;
            cw00 = (yv0 && xv0) ? wy0 * wx0 : 0.f;
            cw01 = (yv0 && xv1) ? wy0 * wx1 : 0.f;
            cw10 = (yv1 && xv0) ? wy1 * wx0 : 0.f;
            cw11 = (yv1 && xv1) ? wy1 * wx1 : 0.f;
        }
        const uint4* gp = (const uint4*)(wTg + (((size_t)q * 256 + wo) << 5) + (whalf << 4));
        uint4 wv0 = gp[0], wv1 = gp[1];
        const int cc = cb * 32 + scq * 4;
        uint2 r00 = *(const uint2*)&sp[(long)a00 * 256 + cc];
        uint2 r01 = *(const uint2*)&sp[(long)a01 * 256 + cc];
        uint2 r10 = *(const uint2*)&sp[(long)a10 * 256 + cc];
        uint2 r11 = *(const uint2*)&sp[(long)a11 * 256 + cc];
        *(uint4*)&Wl[b][wo * 40 + whalf * 16]     = wv0;
        *(uint4*)&Wl[b][wo * 40 + whalf * 16 + 8] = wv1;
        u32 c00[2] = {r00.x, r00.y}, c01[2] = {r01.x, r01.y};
        u32 c10[2] = {r10.x, r10.y}, c11[2] = {r11.x, r11.y};
        u16 pk[4];
        #pragma unroll
        for (int u = 0; u < 4; ++u) {
            int hi = u >> 1, sh = (u & 1) << 4;
            float v00 = bf2f((u16)(c00[hi] >> sh));
            float v01 = bf2f((u16)(c01[hi] >> sh));
            float v10 = bf2f((u16)(c10[hi] >> sh));
            float v11 = bf2f((u16)(c11[hi] >> sh));
            pk[u] = f2bf(fmaf(cw00, v00, fmaf(cw01, v01, fmaf(cw10, v10, cw11 * v11))));
        }
        uint2 pkk;
        pkk.x = (u32)pk[0] | ((u32)pk[1] << 16);
        pkk.y = (u32)pk[2] | ((u32)pk[3] << 16);
        *(uint2*)&Sl[b][sw * 40 + scq * 4] = pkk;
    };

    auto compute = [&](int b) {
        bf16x8 av0 = *(const bf16x8*)&Wl[b][(o0 + l16) * 40 + quad * 8];
        bf16x8 av1 = *(const bf16x8*)&Wl[b][(o0 + 16 + l16) * 40 + quad * 8];
        #pragma unroll
        for (int j = 0; j < 4; ++j) {
            bf16x8 bv = *(const bf16x8*)&Sl[b][(j * 16 + l16) * 40 + quad * 8];
            acc[0][j] = __builtin_amdgcn_mfma_f32_16x16x32_bf16(av0, bv, acc[0][j], 0, 0, 0);
            acc[1][j] = __builtin_amdgcn_mfma_f32_16x16x32_bf16(av1, bv, acc[1][j], 0, 0, 0);
        }
    };

    stage(0, 0);
    __syncthreads();
    for (int q = 0; q < 72; ++q) {
        if (q + 1 < 72) stage(q + 1, (q + 1) & 1);
        compute(q & 1);
        __syncthreads();
    }

    #pragma unroll
    for (int i = 0; i < 2; ++i)
        #pragma unroll
        for (int j = 0; j < 4; ++j)
            #pragma unroll
            for (int r = 0; r < 4; ++r) {
                int o = o0 + i * 16 + quad * 4 + r;
                raw[nbase + ((long)o << 12) + (h << 6) + j * 16 + l16] = f2bf(acc[i][j][r]);
            }
}

// ---------------------------------------------------------------------------
__global__ __launch_bounds__(256) void k_gn_stats(const u16* __restrict__ raw,
                                                  float* __restrict__ stats) {
    const int b = blockIdx.x;
    const uint4* base = (const uint4*)(raw + (long)b * 32768);
    const int tid = threadIdx.x;
    float s1 = 0.f, s2 = 0.f;
    for (int i = tid; i < 4096; i += 256) {
        uint4 p = base[i];
        u32 ww[4] = {p.x, p.y, p.z, p.w};
        #pragma unroll
        for (int q = 0; q < 4; ++q) {
            float a = bf2f((u16)(ww[q] & 0xFFFFu));
            float bb = bf2f((u16)(ww[q] >> 16));
            s1 += a + bb;
            s2 += a * a + bb * bb;
        }
    }
    #pragma unroll
    for (int off = 32; off; off >>= 1) {
        s1 += __shfl_down(s1, off, 64);
        s2 += __shfl_down(s2, off, 64);
    }
    __shared__ float r1[4], r2[4];
    if ((tid & 63) == 0) { r1[tid >> 6] = s1; r2[tid >> 6] = s2; }
    __syncthreads();
    if (tid == 0) {
        float t1 = r1[0] + r1[1] + r1[2] + r1[3];
        float t2 = r2[0] + r2[1] + r2[2] + r2[3];
        const float inv = 1.f / 32768.f;
        float mean = t1 * inv;
        float var = t2 * inv - mean * mean;
        stats[b * 2] = mean;
        stats[b * 2 + 1] = rsqrtf(var + 1e-5f);
    }
}

// ---------------------------------------------------------------------------
// GN + relu; raw (NCHW bf16) -> out1 (NHWC bf16) via LDS transpose.
// ---------------------------------------------------------------------------
__global__ __launch_bounds__(256) void k_gn_relu(
    const u16* __restrict__ raw, const float* __restrict__ stats,
    const void* __restrict__ gamma, const void* __restrict__ beta,
    const u32* __restrict__ flag,
    u16* __restrict__ out1)
{
    __shared__ u16 T[64 * 258];
    const int f32 = (int)flag[0];
    const int bid = blockIdx.x;
    const int n = bid >> 6, h = bid & 63;
    const int tid = threadIdx.x;
    const u16* rb = raw + (long)n * CHW + (h << 6);
    for (int it = 0; it < 64; ++it) {
        int e = it * 256 + tid;
        int c = e >> 6, w = e & 63;
        int ng = n * 32 + (c >> 3);
        float rstd = stats[ng * 2 + 1];
        float ga = loadv(gamma, c, f32) * rstd;
        float be = loadv(beta, c, f32) - stats[ng * 2] * ga;
        float v = fmaxf(fmaf(bf2f(rb[(long)c * HW + w]), ga, be), 0.f);
        T[w * 258 + c] = f2bf(v);
    }
    __syncthreads();
    const int w = tid >> 2, cq = tid & 3;
    const u32* Tr = (const u32*)T;
    u16* ob = out1 + (long)n * CHW + (long)((h << 6) + w) * 256 + cq * 64;
    #pragma unroll
    for (int s = 0; s < 8; ++s) {
        uint4 o;
        o.x = Tr[129 * w + 32 * cq + 4 * s + 0];
        o.y = Tr[129 * w + 32 * cq + 4 * s + 1];
        o.z = Tr[129 * w + 32 * cq + 4 * s + 2];
        o.w = Tr[129 * w + 32 * cq + 4 * s + 3];
        *(uint4*)&ob[s * 8] = o;
    }
}

// ---------------------------------------------------------------------------
__global__ __launch_bounds__(256) void k_gn_final(
    const u16* __restrict__ raw, const float* __restrict__ stats,
    const void* __restrict__ gamma, const void* __restrict__ beta,
    const void* __restrict__ x, const u32* __restrict__ flag,
    void* __restrict__ outp)
{
    const int f32 = (int)flag[0];
    const int i = blockIdx.x * 256 + threadIdx.x;
    const int e = i << 3;
    const int c = (e >> 12) & 255;
    const int ng = (e >> 20) * 32 + (c >> 3);
    float mean = stats[ng * 2], rstd = stats[ng * 2 + 1];
    float ga = loadv(gamma, c, f32) * rstd;
    float be = loadv(beta, c, f32) - mean * ga;
    uint4 p = ((const uint4*)raw)[i];
    u32 ww[4] = {p.x, p.y, p.z, p.w};
    float v[8];
    #pragma unroll
    for (int q = 0; q < 4; ++q) {
        v[2 * q + 0] = fmaxf(fmaf(bf2f((u16)(ww[q] & 0xFFFFu)), ga, be) + loadv(x, (long)e + 2 * q + 0, f32), 0.f);
        v[2 * q + 1] = fmaxf(fmaf(bf2f((u16)(ww[q] >> 16)),     ga, be) + loadv(x, (long)e + 2 * q + 1, f32), 0.f);
    }
    if (f32) {
        float4* op = (float4*)((float*)outp + e);
        op[0] = make_float4(v[0], v[1], v[2], v[3]);
        op[1] = make_float4(v[4], v[5], v[6], v[7]);
    } else {
        uint4 o;
        o.x = (u32)f2bf(v[0]) | ((u32)f2bf(v[1]) << 16);
        o.y = (u32)f2bf(v[2]) | ((u32)f2bf(v[3]) << 16);
        o.z = (u32)f2bf(v[4]) | ((u32)f2bf(v[5]) << 16);
        o.w = (u32)f2bf(v[6]) | ((u32)f2bf(v[7]) << 16);
        ((uint4*)outp)[i] = o;
    }
}

extern "C" void kernel_launch(void* const* d_in, const int* in_sizes, int n_in,
                              void* d_out, int out_size, void* d_ws, size_t ws_size,
                              hipStream_t stream) {
    const void* x     = d_in[0];
    const void* w_tm1 = d_in[1];
    const void* b_tm1 = d_in[2];
    const void* w_tr1 = d_in[3];
    const void* b_tr1 = d_in[4];
    const void* w_dc1 = d_in[5];
    const void* g1    = d_in[6];
    const void* be1   = d_in[7];
    const void* w_tm2 = d_in[8];
    const void* b_tm2 = d_in[9];
    const void* w_tr2 = d_in[10];
    const void* b_tr2 = d_in[11];
    const void* w_dc2 = d_in[12];
    const void* g2    = d_in[13];
    const void* be2   = d_in[14];

    char* wsb = (char*)d_ws;
    u16*   xT    = (u16*)wsb;                                   // 8,388,608 B (alias out1)
    u16*   raw   = (u16*)(wsb + 8388608);                       // 8,388,608 B
    u16*   wTg   = (u16*)(wsb + 16777216);                      // 1,179,648 B
    float* tmtr  = (float*)(wsb + 16777216 + 1179648);          //   393,216 B
    float* stats = (float*)(wsb + 16777216 + 1179648 + 393216); //     1,024 B
    u32*   flag  = (u32*)(wsb + 16777216 + 1179648 + 393216 + 1024);   // 16 B
    u16*   wT6   = (u16*)(wsb + 16777216 + 1179648 + 393216 + 1024 + 16); // 73,728 B
    u16*   out1  = xT;

    k_probe<<<1, 256, 0, stream>>>((const u32*)x, flag);

    // ---- round 1 ----
    k_to_nhwc <<<2048, 256, 0, stream>>>(x, flag, xT);
    k_prep_w  <<<2304, 256, 0, stream>>>(w_dc1, flag, wTg);
    k_prep_w6 <<<144, 256, 0, stream>>>(w_tm1, w_tr1, flag, wT6);
    k_conv6   <<<256, 512, 0, stream>>>(xT, wT6, b_tm1, b_tr1, flag, tmtr);
    k_deform  <<<256, 512, 0, stream>>>(xT, tmtr, wTg, raw);
    k_gn_stats<<<128, 256, 0, stream>>>(raw, stats);
    k_gn_relu <<<256, 256, 0, stream>>>(raw, stats, g1, be1, flag, out1);
    // ---- round 2 ----
    k_prep_w  <<<2304, 256, 0, stream>>>(w_dc2, flag, wTg);
    k_prep_w6 <<<144, 256, 0, stream>>>(w_tm2, w_tr2, flag, wT6);
    k_conv6   <<<256, 512, 0, stream>>>(out1, wT6, b_tm2, b_tr2, flag, tmtr);
    k_deform  <<<256, 512, 0, stream>>>(out1, tmtr, wTg, raw);
    k_gn_stats<<<128, 256, 0, stream>>>(raw, stats);
    k_gn_final<<<2048, 256, 0, stream>>>(raw, stats, g2, be2, x, flag, d_out);
}

// Round 7
// 304.734 us; speedup vs baseline: 4.5273x; 1.0919x over previous
//
#include <hip/hip_runtime.h>

// NHWC MFMA pipeline. Deform conv v3: no W-staging LDS (A-frags direct from
// L2-resident packed weights), 512 blocks (2/CU), software-pipelined sampling.
// ws: xT/out1 (NHWC bf16, aliased) 8 MB | raw (NCHW bf16) 8 MB | wTg 1.18 MB |
//     tmtr 0.39 MB | stats 1 KB | flag 16 B | wT6 73,728 B  (~17.6 MiB)

typedef unsigned int u32;
typedef unsigned short u16;
typedef __attribute__((ext_vector_type(8))) short bf16x8;
typedef __attribute__((ext_vector_type(4))) float floatx4;

#define HW 4096
#define CHW 1048576

static __device__ __forceinline__ float bf2f(u16 u) {
    union { u32 i; float f; } c; c.i = ((u32)u) << 16; return c.f;
}
static __device__ __forceinline__ u16 f2bf(float f) {
    union { float f; u32 i; } c; c.f = f;
    u32 x = c.i;
    return (u16)((x + 0x7FFFu + ((x >> 16) & 1u)) >> 16);   // RNE
}
static __device__ __forceinline__ float loadv(const void* p, long i, int f32) {
    return f32 ? ((const float*)p)[i] : bf2f(((const u16*)p)[i]);
}

__global__ __launch_bounds__(256) void k_probe(const u32* __restrict__ xw,
                                               u32* __restrict__ flag) {
    __shared__ int cnt;
    if (threadIdx.x == 0) cnt = 0;
    __syncthreads();
    union { u32 i; float f; } c;
    c.i = xw[threadIdx.x * 997];
    float a = fabsf(c.f);
    if (a > 1e-8f && a < 1e4f) atomicAdd(&cnt, 1);
    __syncthreads();
    if (threadIdx.x == 0) { flag[0] = (cnt >= 128) ? 1u : 0u; flag[1] = 0u; }
}

// ---------------------------------------------------------------------------
// NCHW (flag dtype) -> NHWC bf16.
// ---------------------------------------------------------------------------
__global__ __launch_bounds__(256) void k_to_nhwc(const void* __restrict__ src,
                                                 const u32* __restrict__ flag,
                                                 u16* __restrict__ dst) {
    const int f32 = (int)flag[0];
    int i = blockIdx.x * 256 + threadIdx.x;
    int cq  = i & 31;
    int pix = i >> 5;
    int n   = pix >> 12;
    int hw  = pix & 4095;
    long sbase = (long)n * CHW + hw;
    u16 v[8];
    #pragma unroll
    for (int j = 0; j < 8; ++j)
        v[j] = f2bf(loadv(src, sbase + (long)(cq * 8 + j) * HW, f32));
    uint4 o;
    o.x = (u32)v[0] | ((u32)v[1] << 16);
    o.y = (u32)v[2] | ((u32)v[3] << 16);
    o.z = (u32)v[4] | ((u32)v[5] << 16);
    o.w = (u32)v[6] | ((u32)v[7] << 16);
    *(uint4*)&dst[(long)n * CHW + (long)hw * 256 + cq * 8] = o;
}

// ---------------------------------------------------------------------------
// Pack deform weights: w_dc [o][c][kk] -> wTg[(kk*8 + c/32)*256 + o][c%32]
// ---------------------------------------------------------------------------
__global__ __launch_bounds__(256) void k_prep_w(const void* __restrict__ wdc,
                                                const u32* __restrict__ flag,
                                                u16* __restrict__ wTg) {
    const int f32 = (int)flag[0];
    int i = blockIdx.x * 256 + threadIdx.x;   // 2304 blocks
    int o = i / 2304;
    int r = i - o * 2304;
    int c = r / 9;
    int kk = r - c * 9;
    wTg[((((kk << 3) + (c >> 5)) * 256 + o) << 5) + (c & 31)] = f2bf(loadv(wdc, i, f32));
}

// ---------------------------------------------------------------------------
// Pack offset-conv weights: [oc][c][k] -> wT6[q][o(16)][c%32]
// ---------------------------------------------------------------------------
__global__ __launch_bounds__(256) void k_prep_w6(const void* __restrict__ w_tm,
                                                 const void* __restrict__ w_tr,
                                                 const u32* __restrict__ flag,
                                                 u16* __restrict__ wT6) {
    const int f32 = (int)flag[0];
    int i = blockIdx.x * 256 + threadIdx.x;   // 144 blocks = 36864
    int q  = i >> 9;
    int o  = (i >> 5) & 15;
    int cc = i & 31;
    int k  = q >> 3;
    int c  = ((q & 7) << 5) + cc;
    float v = 0.f;
    if (o < 4)      v = loadv(w_tm, (long)o * 2304 + c * 9 + k, f32);
    else if (o < 6) v = loadv(w_tr, (long)(o - 4) * 2304 + c * 9 + k, f32);
    wT6[i] = f2bf(v);
}

// ---------------------------------------------------------------------------
// MFMA offset conv: D[6][64] per (n,h) row. (unchanged from round 6)
// ---------------------------------------------------------------------------
__global__ __launch_bounds__(512) void k_conv6(
    const u16* __restrict__ srcT, const u16* __restrict__ wT6,
    const void* __restrict__ b_tm, const void* __restrict__ b_tr,
    const u32* __restrict__ flag,
    float* __restrict__ tmtr)
{
    __shared__ float red[8][64][17];
    const int tid = threadIdx.x;
    const int bid = blockIdx.x;
    const int n = bid >> 6, h = bid & 63;
    const int wv = tid >> 6;
    const int lane = tid & 63;
    const int quad = lane >> 4;
    const int l16 = lane & 15;
    const u16* sp = srcT + (long)n * CHW;

    floatx4 acc[4];
    #pragma unroll
    for (int j4 = 0; j4 < 4; ++j4) acc[j4] = (floatx4){0.f, 0.f, 0.f, 0.f};

    for (int qi = 0; qi < 9; ++qi) {
        const int q = wv * 9 + qi;
        const int k = q >> 3, cb = q & 7;
        const int ky = k / 3, kx = k % 3;
        const int row = h + ky - 1;
        const bool rv = (row >= 0) && (row < 64);
        bf16x8 av = *(const bf16x8*)&wT6[(((q << 4) + l16) << 5) + (quad << 3)];
        #pragma unroll
        for (int j4 = 0; j4 < 4; ++j4) {
            int w = (j4 << 4) + l16;
            int px = w + kx - 1;
            bf16x8 bv = {0, 0, 0, 0, 0, 0, 0, 0};
            if (rv && px >= 0 && px < 64)
                bv = *(const bf16x8*)&sp[(((long)(row << 6) + px) << 8) + (cb << 5) + (quad << 3)];
            acc[j4] = __builtin_amdgcn_mfma_f32_16x16x32_bf16(av, bv, acc[j4], 0, 0, 0);
        }
    }
    #pragma unroll
    for (int j4 = 0; j4 < 4; ++j4)
        #pragma unroll
        for (int r = 0; r < 4; ++r)
            red[wv][lane][(j4 << 2) + r] = acc[j4][r];
    __syncthreads();
    if (tid < 384) {
        const int o = tid >> 6, w = tid & 63;
        const int ln = ((o >> 2) << 4) + (w & 15);
        const int slot = ((w >> 4) << 2) + (o & 3);
        float s = 0.f;
        #pragma unroll
        for (int v = 0; v < 8; ++v) s += red[v][ln][slot];
        const int f32 = (int)flag[0];
        float bias = (o < 4) ? loadv(b_tm, o, f32) : loadv(b_tr, o - 4, f32);
        tmtr[((long)n * 6 + o) * HW + (h << 6) + w] = s + bias;
    }
}

// ---------------------------------------------------------------------------
// MFMA deform conv v3.  Grid 512: block = (n, h, px-half).  8 waves; each wave
// computes 32o x 32px.  A-frags straight from wTg (L2); LDS only for sampled
// S (double-buffered) + geometry.  Software-pipelined: next chunk's global
// loads issued before this chunk's MFMA.
// ---------------------------------------------------------------------------
__global__ __launch_bounds__(512, 4) void k_deform(
    const u16* __restrict__ srcT, const float* __restrict__ tmtr,
    const u16* __restrict__ wTg, u16* __restrict__ raw)
{
    __shared__ __align__(16) short Sl[2][32 * 40];   // 5120 B
    __shared__ int   g_y0[288];
    __shared__ int   g_x0[288];
    __shared__ float g_wy[288];
    __shared__ float g_wx[288];

    const int tid = threadIdx.x;
    const int bid = blockIdx.x;                 // n*128 + h*2 + half
    const int n = bid >> 7, h = (bid >> 1) & 63, half = bid & 1;
    const float* tb = tmtr + (long)n * 6 * HW + (h << 6) + (half << 5);

    for (int i = tid; i < 288; i += 512) {      // geometry for 9k x 32px
        int k = i >> 5, ww2 = i & 31;
        float m00 = tb[ww2],          m01 = tb[HW + ww2];
        float m10 = tb[2 * HW + ww2], m11 = tb[3 * HW + ww2];
        float tr0 = tb[4 * HW + ww2], tr1 = tb[5 * HW + ww2];
        float ry = (float)(k / 3) - 1.f;
        float rx = (float)(k % 3) - 1.f;
        float dy = m00 * ry + m01 * rx - ry + tr0;
        float dx = m10 * ry + m11 * rx - rx + tr1;
        float py = (float)h + ry + dy;
        float px = (float)((half << 5) + ww2) + rx + dx;
        float y0f = floorf(py), x0f = floorf(px);
        g_y0[i] = (int)y0f; g_x0[i] = (int)x0f;
        g_wy[i] = py - y0f; g_wx[i] = px - x0f;
    }
    __syncthreads();

    const long nbase = (long)n * CHW;
    const u16* sp = srcT + nbase;
    // sampler role: px = tid>>4 (0..31), channel pair = tid&15
    const int sw  = tid >> 4;
    const int scq = tid & 15;
    // MFMA role
    const int lane = tid & 63;
    const int quad = lane >> 4;
    const int l16  = lane & 15;
    const int o0   = (tid >> 6) << 5;           // wave o-base (32 o's)

    floatx4 acc[2][2];
    #pragma unroll
    for (int i = 0; i < 2; ++i)
        #pragma unroll
        for (int j = 0; j < 2; ++j)
            acc[i][j] = (floatx4){0.f, 0.f, 0.f, 0.f};

    // sampler per-k state
    int a00 = 0, a01 = 0, a10 = 0, a11 = 0;
    float cw00 = 0.f, cw01 = 0.f, cw10 = 0.f, cw11 = 0.f;
    int cur_k = -1;
    // prefetched values
    u32 s00 = 0, s01 = 0, s10 = 0, s11 = 0;
    bf16x8 wa = {0,0,0,0,0,0,0,0}, wb = {0,0,0,0,0,0,0,0};

    auto issue = [&](int q) {
        const int k = q >> 3;
        if (k != cur_k) {
            cur_k = k;
            int gi = (k << 5) + sw;
            int y0 = g_y0[gi], x0 = g_x0[gi];
            float wy1 = g_wy[gi], wx1 = g_wx[gi];
            float wy0 = 1.f - wy1, wx0 = 1.f - wx1;
            bool yv0 = (y0 >= 0) && (y0 < 64);
            bool yv1 = (y0 >= -1) && (y0 < 63);
            bool xv0 = (x0 >= 0) && (x0 < 64);
            bool xv1 = (x0 >= -1) && (x0 < 63);
            int yc0 = min(max(y0, 0), 63),     yc1 = min(max(y0 + 1, 0), 63);
            int xc0 = min(max(x0, 0), 63),     xc1 = min(max(x0 + 1, 0), 63);
            a00 = yc0 * 64 + xc0; a01 = yc0 * 64 + xc1;
            a10 = yc1 * 64 + xc0; a11 = yc1 * 64 + xc1;
            cw00 = (yv0 && xv0) ? wy0 * wx0 : 0.f;
            cw01 = (yv0 && xv1) ? wy0 * wx1 : 0.f;
            cw10 = (yv1 && xv0) ? wy1 * wx0 : 0.f;
            cw11 = (yv1 && xv1) ? wy1 * wx1 : 0.f;
        }
        const int cc = ((q & 7) << 5) + (scq << 1);   // 2 channels
        s00 = *(const u32*)&sp[(long)a00 * 256 + cc];
        s01 = *(const u32*)&sp[(long)a01 * 256 + cc];
        s10 = *(const u32*)&sp[(long)a10 * 256 + cc];
        s11 = *(const u32*)&sp[(long)a11 * 256 + cc];
        const u16* wp = wTg + (((size_t)q * 256 + o0 + l16) << 5) + (quad << 3);
        wa = *(const bf16x8*)wp;
        wb = *(const bf16x8*)(wp + (16 << 5));
    };
    auto publish = [&](int b) {
        float va = fmaf(cw00, bf2f((u16)s00),
                   fmaf(cw01, bf2f((u16)s01),
                   fmaf(cw10, bf2f((u16)s10), cw11 * bf2f((u16)s11))));
        float vb = fmaf(cw00, bf2f((u16)(s00 >> 16)),
                   fmaf(cw01, bf2f((u16)(s01 >> 16)),
                   fmaf(cw10, bf2f((u16)(s10 >> 16)), cw11 * bf2f((u16)(s11 >> 16)))));
        *(u32*)&Sl[b][sw * 40 + (scq << 1)] = (u32)f2bf(va) | ((u32)f2bf(vb) << 16);
    };

    issue(0);
    publish(0);
    bf16x8 A0 = wa, A1 = wb;
    __syncthreads();

    for (int q = 0; q < 72; ++q) {
        if (q + 1 < 72) issue(q + 1);
        {   // compute chunk q from Sl[q&1] with A0/A1
            const int b = q & 1;
            #pragma unroll
            for (int j = 0; j < 2; ++j) {
                bf16x8 bv = *(const bf16x8*)&Sl[b][((j << 4) + l16) * 40 + (quad << 3)];
                acc[0][j] = __builtin_amdgcn_mfma_f32_16x16x32_bf16(A0, bv, acc[0][j], 0, 0, 0);
                acc[1][j] = __builtin_amdgcn_mfma_f32_16x16x32_bf16(A1, bv, acc[1][j], 0, 0, 0);
            }
        }
        if (q + 1 < 72) { publish((q + 1) & 1); A0 = wa; A1 = wb; }
        __syncthreads();
    }

    // epilogue: o = o0 + i*16 + quad*4 + r, w = half*32 + j*16 + l16
    #pragma unroll
    for (int i = 0; i < 2; ++i)
        #pragma unroll
        for (int j = 0; j < 2; ++j)
            #pragma unroll
            for (int r = 0; r < 4; ++r) {
                int o = o0 + i * 16 + quad * 4 + r;
                raw[nbase + ((long)o << 12) + (h << 6) + (half << 5) + (j << 4) + l16]
                    = f2bf(acc[i][j][r]);
            }
}

// ---------------------------------------------------------------------------
__global__ __launch_bounds__(256) void k_gn_stats(const u16* __restrict__ raw,
                                                  float* __restrict__ stats) {
    const int b = blockIdx.x;
    const uint4* base = (const uint4*)(raw + (long)b * 32768);
    const int tid = threadIdx.x;
    float s1 = 0.f, s2 = 0.f;
    for (int i = tid; i < 4096; i += 256) {
        uint4 p = base[i];
        u32 ww[4] = {p.x, p.y, p.z, p.w};
        #pragma unroll
        for (int q = 0; q < 4; ++q) {
            float a = bf2f((u16)(ww[q] & 0xFFFFu));
            float bb = bf2f((u16)(ww[q] >> 16));
            s1 += a + bb;
            s2 += a * a + bb * bb;
        }
    }
    #pragma unroll
    for (int off = 32; off; off >>= 1) {
        s1 += __shfl_down(s1, off, 64);
        s2 += __shfl_down(s2, off, 64);
    }
    __shared__ float r1[4], r2[4];
    if ((tid & 63) == 0) { r1[tid >> 6] = s1; r2[tid >> 6] = s2; }
    __syncthreads();
    if (tid == 0) {
        float t1 = r1[0] + r1[1] + r1[2] + r1[3];
        float t2 = r2[0] + r2[1] + r2[2] + r2[3];
        const float inv = 1.f / 32768.f;
        float mean = t1 * inv;
        float var = t2 * inv - mean * mean;
        stats[b * 2] = mean;
        stats[b * 2 + 1] = rsqrtf(var + 1e-5f);
    }
}

// ---------------------------------------------------------------------------
// GN + relu; raw (NCHW bf16) -> out1 (NHWC bf16) via LDS transpose.
// ---------------------------------------------------------------------------
__global__ __launch_bounds__(256) void k_gn_relu(
    const u16* __restrict__ raw, const float* __restrict__ stats,
    const void* __restrict__ gamma, const void* __restrict__ beta,
    const u32* __restrict__ flag,
    u16* __restrict__ out1)
{
    __shared__ u16 T[64 * 258];
    const int f32 = (int)flag[0];
    const int bid = blockIdx.x;
    const int n = bid >> 6, h = bid & 63;
    const int tid = threadIdx.x;
    const u16* rb = raw + (long)n * CHW + (h << 6);
    for (int it = 0; it < 64; ++it) {
        int e = it * 256 + tid;
        int c = e >> 6, w = e & 63;
        int ng = n * 32 + (c >> 3);
        float rstd = stats[ng * 2 + 1];
        float ga = loadv(gamma, c, f32) * rstd;
        float be = loadv(beta, c, f32) - stats[ng * 2] * ga;
        float v = fmaxf(fmaf(bf2f(rb[(long)c * HW + w]), ga, be), 0.f);
        T[w * 258 + c] = f2bf(v);
    }
    __syncthreads();
    const int w = tid >> 2, cq = tid & 3;
    const u32* Tr = (const u32*)T;
    u16* ob = out1 + (long)n * CHW + (long)((h << 6) + w) * 256 + cq * 64;
    #pragma unroll
    for (int s = 0; s < 8; ++s) {
        uint4 o;
        o.x = Tr[129 * w + 32 * cq + 4 * s + 0];
        o.y = Tr[129 * w + 32 * cq + 4 * s + 1];
        o.z = Tr[129 * w + 32 * cq + 4 * s + 2];
        o.w = Tr[129 * w + 32 * cq + 4 * s + 3];
        *(uint4*)&ob[s * 8] = o;
    }
}

// ---------------------------------------------------------------------------
__global__ __launch_bounds__(256) void k_gn_final(
    const u16* __restrict__ raw, const float* __restrict__ stats,
    const void* __restrict__ gamma, const void* __restrict__ beta,
    const void* __restrict__ x, const u32* __restrict__ flag,
    void* __restrict__ outp)
{
    const int f32 = (int)flag[0];
    const int i = blockIdx.x * 256 + threadIdx.x;
    const int e = i << 3;
    const int c = (e >> 12) & 255;
    const int ng = (e >> 20) * 32 + (c >> 3);
    float mean = stats[ng * 2], rstd = stats[ng * 2 + 1];
    float ga = loadv(gamma, c, f32) * rstd;
    float be = loadv(beta, c, f32) - mean * ga;
    uint4 p = ((const uint4*)raw)[i];
    u32 ww[4] = {p.x, p.y, p.z, p.w};
    float v[8];
    #pragma unroll
    for (int q = 0; q < 4; ++q) {
        v[2 * q + 0] = fmaxf(fmaf(bf2f((u16)(ww[q] & 0xFFFFu)), ga, be) + loadv(x, (long)e + 2 * q + 0, f32), 0.f);
        v[2 * q + 1] = fmaxf(fmaf(bf2f((u16)(ww[q] >> 16)),     ga, be) + loadv(x, (long)e + 2 * q + 1, f32), 0.f);
    }
    if (f32) {
        float4* op = (float4*)((float*)outp + e);
        op[0] = make_float4(v[0], v[1], v[2], v[3]);
        op[1] = make_float4(v[4], v[5], v[6], v[7]);
    } else {
        uint4 o;
        o.x = (u32)f2bf(v[0]) | ((u32)f2bf(v[1]) << 16);
        o.y = (u32)f2bf(v[2]) | ((u32)f2bf(v[3]) << 16);
        o.z = (u32)f2bf(v[4]) | ((u32)f2bf(v[5]) << 16);
        o.w = (u32)f2bf(v[6]) | ((u32)f2bf(v[7]) << 16);
        ((uint4*)outp)[i] = o;
    }
}

extern "C" void kernel_launch(void* const* d_in, const int* in_sizes, int n_in,
                              void* d_out, int out_size, void* d_ws, size_t ws_size,
                              hipStream_t stream) {
    const void* x     = d_in[0];
    const void* w_tm1 = d_in[1];
    const void* b_tm1 = d_in[2];
    const void* w_tr1 = d_in[3];
    const void* b_tr1 = d_in[4];
    const void* w_dc1 = d_in[5];
    const void* g1    = d_in[6];
    const void* be1   = d_in[7];
    const void* w_tm2 = d_in[8];
    const void* b_tm2 = d_in[9];
    const void* w_tr2 = d_in[10];
    const void* b_tr2 = d_in[11];
    const void* w_dc2 = d_in[12];
    const void* g2    = d_in[13];
    const void* be2   = d_in[14];

    char* wsb = (char*)d_ws;
    u16*   xT    = (u16*)wsb;                                   // 8,388,608 B (alias out1)
    u16*   raw   = (u16*)(wsb + 8388608);                       // 8,388,608 B
    u16*   wTg   = (u16*)(wsb + 16777216);                      // 1,179,648 B
    float* tmtr  = (float*)(wsb + 16777216 + 1179648);          //   393,216 B
    float* stats = (float*)(wsb + 16777216 + 1179648 + 393216); //     1,024 B
    u32*   flag  = (u32*)(wsb + 16777216 + 1179648 + 393216 + 1024);   // 16 B
    u16*   wT6   = (u16*)(wsb + 16777216 + 1179648 + 393216 + 1024 + 16); // 73,728 B
    u16*   out1  = xT;

    k_probe<<<1, 256, 0, stream>>>((const u32*)x, flag);

    // ---- round 1 ----
    k_to_nhwc <<<2048, 256, 0, stream>>>(x, flag, xT);
    k_prep_w  <<<2304, 256, 0, stream>>>(w_dc1, flag, wTg);
    k_prep_w6 <<<144, 256, 0, stream>>>(w_tm1, w_tr1, flag, wT6);
    k_conv6   <<<256, 512, 0, stream>>>(xT, wT6, b_tm1, b_tr1, flag, tmtr);
    k_deform  <<<512, 512, 0, stream>>>(xT, tmtr, wTg, raw);
    k_gn_stats<<<128, 256, 0, stream>>>(raw, stats);
    k_gn_relu <<<256, 256, 0, stream>>>(raw, stats, g1, be1, flag, out1);
    // ---- round 2 ----
    k_prep_w  <<<2304, 256, 0, stream>>>(w_dc2, flag, wTg);
    k_prep_w6 <<<144, 256, 0, stream>>>(w_tm2, w_tr2, flag, wT6);
    k_conv6   <<<256, 512, 0, stream>>>(out1, wT6, b_tm2, b_tr2, flag, tmtr);
    k_deform  <<<512, 512, 0, stream>>>(out1, tmtr, wTg, raw);
    k_gn_stats<<<128, 256, 0, stream>>>(raw, stats);
    k_gn_final<<<2048, 256, 0, stream>>>(raw, stats, g2, be2, x, flag, d_out);
}